// Round 1
// baseline (947.387 us; speedup 1.0000x reference)
//
#include <hip/hip_runtime.h>
#include <math.h>

#define NN 50000
#define DIN 256
#define HC 64
#define NEG 0.2f
#define ROWS 32

// ---------------- CSR build ----------------

__global__ __launch_bounds__(256) void hist_k(const int* __restrict__ dst,
                                              int* __restrict__ counts, int E) {
    int e = blockIdx.x * 256 + threadIdx.x;
    if (e < E) atomicAdd(&counts[dst[e]], 1);
}

__global__ __launch_bounds__(1024) void scan_k(const int* __restrict__ counts,
                                               int* __restrict__ offs,
                                               int* __restrict__ cursor, int n) {
    __shared__ int sums[1024];
    int t = threadIdx.x;
    int chunk = (n + 1023) >> 10;
    int lo = min(t * chunk, n);
    int hi = min(lo + chunk, n);
    int s = 0;
    for (int i = lo; i < hi; ++i) s += counts[i];
    sums[t] = s;
    __syncthreads();
    for (int off = 1; off < 1024; off <<= 1) {
        int v = sums[t];
        int u = (t >= off) ? sums[t - off] : 0;
        __syncthreads();
        sums[t] = v + u;
        __syncthreads();
    }
    int prefix = (t == 0) ? 0 : sums[t - 1];
    for (int i = lo; i < hi; ++i) {
        offs[i] = prefix;
        cursor[i] = prefix;
        prefix += counts[i];
    }
    if (t == 1023) offs[n] = sums[1023];
}

__global__ __launch_bounds__(256) void scatter_k(const int* __restrict__ src,
                                                 const int* __restrict__ dst,
                                                 int* __restrict__ cursor,
                                                 int* __restrict__ ssrc, int E) {
    int e = blockIdx.x * 256 + threadIdx.x;
    if (e < E) {
        int d = dst[e];
        int pos = atomicAdd(&cursor[d], 1);
        ssrc[pos] = src[e];
    }
}

// ---------------- dense transforms ----------------
// xl = x@Wl + bl ; xr = x@Wr + br   (x: [n,K], W: [K,64])
// block = 256 threads, 32 rows/block; 16 col-threads x 4 cols; 16 row-groups x 2 rows
__global__ __launch_bounds__(256) void transform_k(const float* __restrict__ x,
                                                   const float* __restrict__ Wl,
                                                   const float* __restrict__ bl,
                                                   const float* __restrict__ Wr,
                                                   const float* __restrict__ br,
                                                   float* __restrict__ xl,
                                                   float* __restrict__ xr,
                                                   int n, int K) {
    __shared__ float xs[ROWS][65];   // +1 pad: rows hit distinct banks
    int t = threadIdx.x;
    int row0 = blockIdx.x * ROWS;
    int jc = (t & 15) * 4;           // col base within 64
    int g = t >> 4;                  // 0..15 row group (2 rows each)
    float accl[2][4] = {};
    float accr[2][4] = {};
    int nchunks = K >> 6;
    for (int kc = 0; kc < nchunks; ++kc) {
        __syncthreads();
        for (int i = t; i < ROWS * 64; i += 256) {
            int r = i >> 6, c = i & 63;
            int gr = row0 + r;
            xs[r][c] = (gr < n) ? x[(size_t)gr * K + kc * 64 + c] : 0.f;
        }
        __syncthreads();
        for (int k = 0; k < 64; ++k) {
            int krow = kc * 64 + k;
            float4 wl = *(const float4*)(Wl + (size_t)krow * HC + jc);
            float4 wr = *(const float4*)(Wr + (size_t)krow * HC + jc);
#pragma unroll
            for (int r = 0; r < 2; ++r) {
                float xv = xs[g * 2 + r][k];
                accl[r][0] += xv * wl.x; accl[r][1] += xv * wl.y;
                accl[r][2] += xv * wl.z; accl[r][3] += xv * wl.w;
                accr[r][0] += xv * wr.x; accr[r][1] += xv * wr.y;
                accr[r][2] += xv * wr.z; accr[r][3] += xv * wr.w;
            }
        }
    }
    float4 bl4 = *(const float4*)(bl + jc);
    float4 br4 = *(const float4*)(br + jc);
#pragma unroll
    for (int r = 0; r < 2; ++r) {
        int gr = row0 + g * 2 + r;
        if (gr < n) {
            float4 ol, orr;
            ol.x = accl[r][0] + bl4.x; ol.y = accl[r][1] + bl4.y;
            ol.z = accl[r][2] + bl4.z; ol.w = accl[r][3] + bl4.w;
            orr.x = accr[r][0] + br4.x; orr.y = accr[r][1] + br4.y;
            orr.z = accr[r][2] + br4.z; orr.w = accr[r][3] + br4.w;
            *(float4*)(xl + (size_t)gr * HC + jc) = ol;
            *(float4*)(xr + (size_t)gr * HC + jc) = orr;
        }
    }
}

// ---------------- edge aggregation (one wave per node) ----------------
// out[n,l] = relu( (sum_e exp(logit_e) * xl[src_e, l]) / (sum_e exp(logit_e)) + bias[l] )
// logit_e(h) = sum_c att[h,c] * leaky_relu(xl[src]+xr[n])
__global__ __launch_bounds__(256) void agg_k(const float* __restrict__ xl,
                                             const float* __restrict__ xr,
                                             const float* __restrict__ att,
                                             const float* __restrict__ bias,
                                             const int* __restrict__ offs,
                                             const int* __restrict__ ssrc,
                                             float* __restrict__ out, int n) {
    int wave = (blockIdx.x * 256 + threadIdx.x) >> 6;
    int lane = threadIdx.x & 63;
    if (wave >= n) return;
    float xrv = xr[(size_t)wave * HC + lane];
    float attv = att[lane];
    float acc = 0.f, den = 0.f;
    int lo = offs[wave], hi = offs[wave + 1];
    for (int i = lo; i < hi; ++i) {
        int j = ssrc[i];
        float xlv = xl[(size_t)j * HC + lane];
        float s = xlv + xrv;
        float lr = s > 0.f ? s : NEG * s;
        float v = attv * lr;
        v += __shfl_xor(v, 1);
        v += __shfl_xor(v, 2);
        v += __shfl_xor(v, 4);
        v += __shfl_xor(v, 8);
        float ex = __expf(v);
        den += ex;
        acc += ex * xlv;
    }
    float o = (den > 0.f) ? acc / den : 0.f;
    o += bias[lane];
    out[(size_t)wave * HC + lane] = fmaxf(o, 0.f);
}

// ---------------- output head ----------------
// out = sigmoid(h @ Wo + bo), h:[n,64], Wo:[64,256]
__global__ __launch_bounds__(256) void head_k(const float* __restrict__ h,
                                              const float* __restrict__ Wo,
                                              const float* __restrict__ bo,
                                              float* __restrict__ out, int n) {
    __shared__ float hs[ROWS][HC];
    int t = threadIdx.x;
    int row0 = blockIdx.x * ROWS;
    for (int i = t; i < ROWS * HC; i += 256) {
        int r = i >> 6, c = i & 63;
        int gr = row0 + r;
        hs[r][c] = (gr < n) ? h[(size_t)gr * HC + c] : 0.f;
    }
    __syncthreads();
    int jc = (t & 63) * 4;   // col base within 256
    int g = t >> 6;          // 0..3, 8 rows each
    float acc[8][4];
    float4 b = *(const float4*)(bo + jc);
#pragma unroll
    for (int r = 0; r < 8; ++r) {
        acc[r][0] = b.x; acc[r][1] = b.y; acc[r][2] = b.z; acc[r][3] = b.w;
    }
    for (int k = 0; k < HC; ++k) {
        float4 w = *(const float4*)(Wo + (size_t)k * DIN + jc);
#pragma unroll
        for (int r = 0; r < 8; ++r) {
            float hv = hs[g * 8 + r][k];
            acc[r][0] += hv * w.x; acc[r][1] += hv * w.y;
            acc[r][2] += hv * w.z; acc[r][3] += hv * w.w;
        }
    }
#pragma unroll
    for (int r = 0; r < 8; ++r) {
        int gr = row0 + g * 8 + r;
        if (gr < n) {
            float4 o;
            o.x = 1.f / (1.f + __expf(-acc[r][0]));
            o.y = 1.f / (1.f + __expf(-acc[r][1]));
            o.z = 1.f / (1.f + __expf(-acc[r][2]));
            o.w = 1.f / (1.f + __expf(-acc[r][3]));
            *(float4*)(out + (size_t)gr * DIN + jc) = o;
        }
    }
}

extern "C" void kernel_launch(void* const* d_in, const int* in_sizes, int n_in,
                              void* d_out, int out_size, void* d_ws, size_t ws_size,
                              hipStream_t stream) {
    const float* x    = (const float*)d_in[0];
    const int*   ei   = (const int*)d_in[1];
    const float* Wl1  = (const float*)d_in[2];
    const float* bl1  = (const float*)d_in[3];
    const float* Wr1  = (const float*)d_in[4];
    const float* br1  = (const float*)d_in[5];
    const float* att1 = (const float*)d_in[6];
    const float* bias1= (const float*)d_in[7];
    const float* Wl2  = (const float*)d_in[8];
    const float* bl2  = (const float*)d_in[9];
    const float* Wr2  = (const float*)d_in[10];
    const float* br2  = (const float*)d_in[11];
    const float* att2 = (const float*)d_in[12];
    const float* bias2= (const float*)d_in[13];
    const float* Wo   = (const float*)d_in[14];
    const float* bo   = (const float*)d_in[15];
    float* out = (float*)d_out;

    int E = in_sizes[1] / 2;
    const int* srcv = ei;
    const int* dstv = ei + E;

    size_t NF = (size_t)NN * HC;
    float* xl = (float*)d_ws;
    float* xr = xl + NF;
    float* hb = xr + NF;                  // h1, later h2
    int* counts = (int*)(hb + NF);
    int* offs   = counts + NN;            // NN+1 entries
    int* cursor = offs + NN + 1;
    int* ssrc   = cursor + NN;            // E entries

    hipMemsetAsync(counts, 0, NN * sizeof(int), stream);
    hist_k<<<(E + 255) / 256, 256, 0, stream>>>(dstv, counts, E);
    scan_k<<<1, 1024, 0, stream>>>(counts, offs, cursor, NN);
    scatter_k<<<(E + 255) / 256, 256, 0, stream>>>(srcv, dstv, cursor, ssrc, E);

    int tb = (NN + ROWS - 1) / ROWS;
    // layer 1
    transform_k<<<tb, 256, 0, stream>>>(x, Wl1, bl1, Wr1, br1, xl, xr, NN, DIN);
    agg_k<<<(NN + 3) / 4, 256, 0, stream>>>(xl, xr, att1, bias1, offs, ssrc, hb, NN);
    // layer 2
    transform_k<<<tb, 256, 0, stream>>>(hb, Wl2, bl2, Wr2, br2, xl, xr, NN, HC);
    agg_k<<<(NN + 3) / 4, 256, 0, stream>>>(xl, xr, att2, bias2, offs, ssrc, hb, NN);
    // head
    head_k<<<tb, 256, 0, stream>>>(hb, Wo, bo, out, NN);
}

// Round 2
// 686.523 us; speedup vs baseline: 1.3800x; 1.3800x over previous
//
#include <hip/hip_runtime.h>
#include <math.h>

#define NN 50000
#define DIN 256
#define HC 64
#define NEG 0.2f
#define TROWS 64

// ---------------- CSR build ----------------

__global__ __launch_bounds__(256) void hist_k(const int* __restrict__ dst,
                                              int* __restrict__ counts, int E) {
    int e = blockIdx.x * 256 + threadIdx.x;
    if (e < E) atomicAdd(&counts[dst[e]], 1);
}

// phase 1: per-1024-chunk sums
__global__ __launch_bounds__(256) void scan1_k(const int* __restrict__ counts,
                                               int* __restrict__ bsum, int n) {
    __shared__ int red[256];
    int b = blockIdx.x, t = threadIdx.x;
    int base = b * 1024 + t * 4;
    int s = 0;
    if (base + 3 < n) {
        int4 v = *(const int4*)(counts + base);
        s = v.x + v.y + v.z + v.w;
    } else {
        for (int k = 0; k < 4; ++k) if (base + k < n) s += counts[base + k];
    }
    red[t] = s; __syncthreads();
    for (int off = 128; off > 0; off >>= 1) {
        if (t < off) red[t] += red[t + off];
        __syncthreads();
    }
    if (t == 0) bsum[b] = red[0];
}

// phase 2: single-wave inclusive scan of block sums (nb <= 64); writes offs[n]
__global__ __launch_bounds__(64) void scan2_k(int* __restrict__ bsum,
                                              int* __restrict__ offs, int nb, int n) {
    int t = threadIdx.x;
    int v = (t < nb) ? bsum[t] : 0;
    for (int off = 1; off < 64; off <<= 1) {
        int u = __shfl_up(v, off);
        if (t >= off) v += u;
    }
    if (t < nb) bsum[t] = v;
    if (t == nb - 1) offs[n] = v;
}

// phase 3: per-chunk exclusive scan + block prefix -> offs, cursor
__global__ __launch_bounds__(256) void scan3_k(const int* __restrict__ counts,
                                               const int* __restrict__ bsum,
                                               int* __restrict__ offs,
                                               int* __restrict__ cursor, int n) {
    __shared__ int lds[256];
    int b = blockIdx.x, t = threadIdx.x;
    int base = b * 1024 + t * 4;
    int c[4] = {0, 0, 0, 0};
    for (int k = 0; k < 4; ++k) if (base + k < n) c[k] = counts[base + k];
    int s = c[0] + c[1] + c[2] + c[3];
    lds[t] = s; __syncthreads();
    for (int off = 1; off < 256; off <<= 1) {
        int v = lds[t];
        int u = (t >= off) ? lds[t - off] : 0;
        __syncthreads();
        lds[t] = v + u;
        __syncthreads();
    }
    int excl = (t == 0 ? 0 : lds[t - 1]) + ((b == 0) ? 0 : bsum[b - 1]);
    for (int k = 0; k < 4; ++k) {
        if (base + k < n) {
            offs[base + k] = excl;
            cursor[base + k] = excl;
            excl += c[k];
        }
    }
}

__global__ __launch_bounds__(256) void scatter_k(const int* __restrict__ src,
                                                 const int* __restrict__ dst,
                                                 int* __restrict__ cursor,
                                                 int* __restrict__ ssrc, int E) {
    int e = blockIdx.x * 256 + threadIdx.x;
    if (e < E) {
        int d = dst[e];
        int pos = atomicAdd(&cursor[d], 1);
        ssrc[pos] = src[e];
    }
}

// ---------------- dense transforms ----------------
// xl = x@Wl + bl ; xr = x@Wr + br   (x: [n,K], W: [K,64])
// block = 256 threads, 64 rows/block; 16 col-threads x 4 cols; 16 row-groups x 4 rows
__global__ __launch_bounds__(256) void transform_k(const float* __restrict__ x,
                                                   const float* __restrict__ Wl,
                                                   const float* __restrict__ bl,
                                                   const float* __restrict__ Wr,
                                                   const float* __restrict__ br,
                                                   float* __restrict__ xl,
                                                   float* __restrict__ xr,
                                                   int n, int K) {
    __shared__ float xs[TROWS][65];   // +1 pad: rows hit distinct banks
    int t = threadIdx.x;
    int row0 = blockIdx.x * TROWS;
    int jc = (t & 15) * 4;           // col base within 64
    int g = t >> 4;                  // 0..15 row group (4 rows each)
    float accl[4][4] = {};
    float accr[4][4] = {};
    int nchunks = K >> 6;
    for (int kc = 0; kc < nchunks; ++kc) {
        __syncthreads();
        for (int i = t; i < TROWS * 64; i += 256) {
            int r = i >> 6, c = i & 63;
            int gr = row0 + r;
            xs[r][c] = (gr < n) ? x[(size_t)gr * K + kc * 64 + c] : 0.f;
        }
        __syncthreads();
        for (int k = 0; k < 64; ++k) {
            int krow = kc * 64 + k;
            float4 wl = *(const float4*)(Wl + (size_t)krow * HC + jc);
            float4 wr = *(const float4*)(Wr + (size_t)krow * HC + jc);
#pragma unroll
            for (int r = 0; r < 4; ++r) {
                float xv = xs[g * 4 + r][k];
                accl[r][0] += xv * wl.x; accl[r][1] += xv * wl.y;
                accl[r][2] += xv * wl.z; accl[r][3] += xv * wl.w;
                accr[r][0] += xv * wr.x; accr[r][1] += xv * wr.y;
                accr[r][2] += xv * wr.z; accr[r][3] += xv * wr.w;
            }
        }
    }
    float4 bl4 = *(const float4*)(bl + jc);
    float4 br4 = *(const float4*)(br + jc);
#pragma unroll
    for (int r = 0; r < 4; ++r) {
        int gr = row0 + g * 4 + r;
        if (gr < n) {
            float4 ol, orr;
            ol.x = accl[r][0] + bl4.x; ol.y = accl[r][1] + bl4.y;
            ol.z = accl[r][2] + bl4.z; ol.w = accl[r][3] + bl4.w;
            orr.x = accr[r][0] + br4.x; orr.y = accr[r][1] + br4.y;
            orr.z = accr[r][2] + br4.z; orr.w = accr[r][3] + br4.w;
            *(float4*)(xl + (size_t)gr * HC + jc) = ol;
            *(float4*)(xr + (size_t)gr * HC + jc) = orr;
        }
    }
}

// ---------------- edge aggregation (one wave per node) ----------------
// 4-edge ILP batching: 4 independent gather+reduce chains in flight.
__global__ __launch_bounds__(256) void agg_k(const float* __restrict__ xl,
                                             const float* __restrict__ xr,
                                             const float* __restrict__ att,
                                             const float* __restrict__ bias,
                                             const int* __restrict__ offs,
                                             const int* __restrict__ ssrc,
                                             float* __restrict__ out, int n) {
    int wave = (blockIdx.x * 256 + threadIdx.x) >> 6;
    int lane = threadIdx.x & 63;
    if (wave >= n) return;
    float xrv = xr[(size_t)wave * HC + lane];
    float attv = att[lane];
    float acc = 0.f, den = 0.f;
    int lo = __builtin_amdgcn_readfirstlane(offs[wave]);
    int hi = __builtin_amdgcn_readfirstlane(offs[wave + 1]);
    int i = lo;
    for (; i + 4 <= hi; i += 4) {
        int j0 = ssrc[i], j1 = ssrc[i + 1], j2 = ssrc[i + 2], j3 = ssrc[i + 3];
        float x0 = xl[(size_t)j0 * HC + lane];
        float x1 = xl[(size_t)j1 * HC + lane];
        float x2 = xl[(size_t)j2 * HC + lane];
        float x3 = xl[(size_t)j3 * HC + lane];
        float s0 = x0 + xrv, s1 = x1 + xrv, s2 = x2 + xrv, s3 = x3 + xrv;
        float v0 = attv * (s0 > 0.f ? s0 : NEG * s0);
        float v1 = attv * (s1 > 0.f ? s1 : NEG * s1);
        float v2 = attv * (s2 > 0.f ? s2 : NEG * s2);
        float v3 = attv * (s3 > 0.f ? s3 : NEG * s3);
        v0 += __shfl_xor(v0, 1); v1 += __shfl_xor(v1, 1);
        v2 += __shfl_xor(v2, 1); v3 += __shfl_xor(v3, 1);
        v0 += __shfl_xor(v0, 2); v1 += __shfl_xor(v1, 2);
        v2 += __shfl_xor(v2, 2); v3 += __shfl_xor(v3, 2);
        v0 += __shfl_xor(v0, 4); v1 += __shfl_xor(v1, 4);
        v2 += __shfl_xor(v2, 4); v3 += __shfl_xor(v3, 4);
        v0 += __shfl_xor(v0, 8); v1 += __shfl_xor(v1, 8);
        v2 += __shfl_xor(v2, 8); v3 += __shfl_xor(v3, 8);
        float e0 = __expf(v0), e1 = __expf(v1), e2 = __expf(v2), e3 = __expf(v3);
        den += (e0 + e1) + (e2 + e3);
        acc += e0 * x0; acc += e1 * x1; acc += e2 * x2; acc += e3 * x3;
    }
    for (; i < hi; ++i) {
        int j = ssrc[i];
        float xlv = xl[(size_t)j * HC + lane];
        float s = xlv + xrv;
        float lr = s > 0.f ? s : NEG * s;
        float v = attv * lr;
        v += __shfl_xor(v, 1);
        v += __shfl_xor(v, 2);
        v += __shfl_xor(v, 4);
        v += __shfl_xor(v, 8);
        float ex = __expf(v);
        den += ex;
        acc += ex * xlv;
    }
    float o = (den > 0.f) ? acc / den : 0.f;
    o += bias[lane];
    out[(size_t)wave * HC + lane] = fmaxf(o, 0.f);
}

// ---------------- output head ----------------
// out = sigmoid(h @ Wo + bo), h:[n,64], Wo:[64,256]
__global__ __launch_bounds__(256) void head_k(const float* __restrict__ h,
                                              const float* __restrict__ Wo,
                                              const float* __restrict__ bo,
                                              float* __restrict__ out, int n) {
    __shared__ float hs[32][HC];
    int t = threadIdx.x;
    int row0 = blockIdx.x * 32;
    for (int i = t; i < 32 * HC; i += 256) {
        int r = i >> 6, c = i & 63;
        int gr = row0 + r;
        hs[r][c] = (gr < n) ? h[(size_t)gr * HC + c] : 0.f;
    }
    __syncthreads();
    int jc = (t & 63) * 4;   // col base within 256
    int g = t >> 6;          // 0..3, 8 rows each
    float acc[8][4];
    float4 b = *(const float4*)(bo + jc);
#pragma unroll
    for (int r = 0; r < 8; ++r) {
        acc[r][0] = b.x; acc[r][1] = b.y; acc[r][2] = b.z; acc[r][3] = b.w;
    }
    for (int k = 0; k < HC; ++k) {
        float4 w = *(const float4*)(Wo + (size_t)k * DIN + jc);
#pragma unroll
        for (int r = 0; r < 8; ++r) {
            float hv = hs[g * 8 + r][k];
            acc[r][0] += hv * w.x; acc[r][1] += hv * w.y;
            acc[r][2] += hv * w.z; acc[r][3] += hv * w.w;
        }
    }
#pragma unroll
    for (int r = 0; r < 8; ++r) {
        int gr = row0 + g * 8 + r;
        if (gr < n) {
            float4 o;
            o.x = 1.f / (1.f + __expf(-acc[r][0]));
            o.y = 1.f / (1.f + __expf(-acc[r][1]));
            o.z = 1.f / (1.f + __expf(-acc[r][2]));
            o.w = 1.f / (1.f + __expf(-acc[r][3]));
            *(float4*)(out + (size_t)gr * DIN + jc) = o;
        }
    }
}

extern "C" void kernel_launch(void* const* d_in, const int* in_sizes, int n_in,
                              void* d_out, int out_size, void* d_ws, size_t ws_size,
                              hipStream_t stream) {
    const float* x    = (const float*)d_in[0];
    const int*   ei   = (const int*)d_in[1];
    const float* Wl1  = (const float*)d_in[2];
    const float* bl1  = (const float*)d_in[3];
    const float* Wr1  = (const float*)d_in[4];
    const float* br1  = (const float*)d_in[5];
    const float* att1 = (const float*)d_in[6];
    const float* bias1= (const float*)d_in[7];
    const float* Wl2  = (const float*)d_in[8];
    const float* bl2  = (const float*)d_in[9];
    const float* Wr2  = (const float*)d_in[10];
    const float* br2  = (const float*)d_in[11];
    const float* att2 = (const float*)d_in[12];
    const float* bias2= (const float*)d_in[13];
    const float* Wo   = (const float*)d_in[14];
    const float* bo   = (const float*)d_in[15];
    float* out = (float*)d_out;

    int E = in_sizes[1] / 2;
    const int* srcv = ei;
    const int* dstv = ei + E;

    size_t NF = (size_t)NN * HC;
    float* xl = (float*)d_ws;
    float* xr = xl + NF;
    float* hb = xr + NF;                  // h1, later h2
    int* counts = (int*)(hb + NF);
    int* offs   = counts + NN;            // NN+1 entries
    int* cursor = offs + NN + 1;
    int* ssrc   = cursor + NN;            // E entries
    int* bsum   = ssrc + E;               // scan block sums

    int nb = (NN + 1023) / 1024;

    hipMemsetAsync(counts, 0, NN * sizeof(int), stream);
    hist_k<<<(E + 255) / 256, 256, 0, stream>>>(dstv, counts, E);
    scan1_k<<<nb, 256, 0, stream>>>(counts, bsum, NN);
    scan2_k<<<1, 64, 0, stream>>>(bsum, offs, nb, NN);
    scan3_k<<<nb, 256, 0, stream>>>(counts, bsum, offs, cursor, NN);
    scatter_k<<<(E + 255) / 256, 256, 0, stream>>>(srcv, dstv, cursor, ssrc, E);

    int tb = (NN + TROWS - 1) / TROWS;
    // layer 1
    transform_k<<<tb, 256, 0, stream>>>(x, Wl1, bl1, Wr1, br1, xl, xr, NN, DIN);
    agg_k<<<(NN + 3) / 4, 256, 0, stream>>>(xl, xr, att1, bias1, offs, ssrc, hb, NN);
    // layer 2
    transform_k<<<tb, 256, 0, stream>>>(hb, Wl2, bl2, Wr2, br2, xl, xr, NN, HC);
    agg_k<<<(NN + 3) / 4, 256, 0, stream>>>(xl, xr, att2, bias2, offs, ssrc, hb, NN);
    // head
    head_k<<<(NN + 31) / 32, 256, 0, stream>>>(hb, Wo, bo, out, NN);
}

// Round 3
// 559.189 us; speedup vs baseline: 1.6942x; 1.2277x over previous
//
#include <hip/hip_runtime.h>
#include <math.h>

#define NN 50000
#define DIN 256
#define HC 64
#define NEG 0.2f
#define BK 16

// ---------------- CSR build ----------------

__global__ __launch_bounds__(256) void hist_k(const int* __restrict__ dst,
                                              int* __restrict__ counts, int E) {
    int e = blockIdx.x * 256 + threadIdx.x;
    if (e < E) atomicAdd(&counts[dst[e]], 1);
}

// phase 1: per-1024-chunk sums
__global__ __launch_bounds__(256) void scan1_k(const int* __restrict__ counts,
                                               int* __restrict__ bsum, int n) {
    __shared__ int red[256];
    int b = blockIdx.x, t = threadIdx.x;
    int base = b * 1024 + t * 4;
    int s = 0;
    if (base + 3 < n) {
        int4 v = *(const int4*)(counts + base);
        s = v.x + v.y + v.z + v.w;
    } else {
        for (int k = 0; k < 4; ++k) if (base + k < n) s += counts[base + k];
    }
    red[t] = s; __syncthreads();
    for (int off = 128; off > 0; off >>= 1) {
        if (t < off) red[t] += red[t + off];
        __syncthreads();
    }
    if (t == 0) bsum[b] = red[0];
}

// phase 2: single-wave inclusive scan of block sums (nb <= 64); writes offs[n]
__global__ __launch_bounds__(64) void scan2_k(int* __restrict__ bsum,
                                              int* __restrict__ offs, int nb, int n) {
    int t = threadIdx.x;
    int v = (t < nb) ? bsum[t] : 0;
    for (int off = 1; off < 64; off <<= 1) {
        int u = __shfl_up(v, off);
        if (t >= off) v += u;
    }
    if (t < nb) bsum[t] = v;
    if (t == nb - 1) offs[n] = v;
}

// phase 3: per-chunk exclusive scan + block prefix -> offs, cursor
__global__ __launch_bounds__(256) void scan3_k(const int* __restrict__ counts,
                                               const int* __restrict__ bsum,
                                               int* __restrict__ offs,
                                               int* __restrict__ cursor, int n) {
    __shared__ int lds[256];
    int b = blockIdx.x, t = threadIdx.x;
    int base = b * 1024 + t * 4;
    int c[4] = {0, 0, 0, 0};
    for (int k = 0; k < 4; ++k) if (base + k < n) c[k] = counts[base + k];
    int s = c[0] + c[1] + c[2] + c[3];
    lds[t] = s; __syncthreads();
    for (int off = 1; off < 256; off <<= 1) {
        int v = lds[t];
        int u = (t >= off) ? lds[t - off] : 0;
        __syncthreads();
        lds[t] = v + u;
        __syncthreads();
    }
    int excl = (t == 0 ? 0 : lds[t - 1]) + ((b == 0) ? 0 : bsum[b - 1]);
    for (int k = 0; k < 4; ++k) {
        if (base + k < n) {
            offs[base + k] = excl;
            cursor[base + k] = excl;
            excl += c[k];
        }
    }
}

__global__ __launch_bounds__(256) void scatter_k(const int* __restrict__ src,
                                                 const int* __restrict__ dst,
                                                 int* __restrict__ cursor,
                                                 int* __restrict__ ssrc, int E) {
    int e = blockIdx.x * 256 + threadIdx.x;
    if (e < E) {
        int d = dst[e];
        int pos = atomicAdd(&cursor[d], 1);
        ssrc[pos] = src[e];
    }
}

// ---------------- tiled dual GEMM: [xl|xr] = A @ [Wl|Wr] + [bl|br] ----------------
// tile 64 rows x 128 cols, BK=16. Each thread: 4 rows x 8 cols.
__global__ __launch_bounds__(256) void gemm_dual_k(const float* __restrict__ A,
                                                   const float* __restrict__ Wl,
                                                   const float* __restrict__ bl,
                                                   const float* __restrict__ Wr,
                                                   const float* __restrict__ br,
                                                   float* __restrict__ xl,
                                                   float* __restrict__ xr,
                                                   int n, int K) {
    __shared__ float As[BK][68];   // transposed, +4 pad -> 2-way (free) staging writes
    __shared__ float Bs[BK][128];
    int t = threadIdx.x;
    int tx = t & 15, ty = t >> 4;
    int row0 = blockIdx.x * 64;
    float acc[4][8] = {};
    int arow = t >> 2;             // 0..63
    int akb  = (t & 3) * 4;        // 0,4,8,12
    int bk   = t >> 4;             // 0..15
    int bcol = (t & 15) * 4;       // 0..60
    bool arow_ok = (row0 + arow) < n;
    const float* Aptr = A + (size_t)(row0 + arow) * K + akb;

    for (int kc = 0; kc < K; kc += BK) {
        float4 av = make_float4(0.f, 0.f, 0.f, 0.f);
        if (arow_ok) av = *(const float4*)(Aptr + kc);
        float4 b0 = *(const float4*)(Wl + (size_t)(kc + bk) * HC + bcol);
        float4 b1 = *(const float4*)(Wr + (size_t)(kc + bk) * HC + bcol);
        __syncthreads();
        As[akb + 0][arow] = av.x;
        As[akb + 1][arow] = av.y;
        As[akb + 2][arow] = av.z;
        As[akb + 3][arow] = av.w;
        *(float4*)&Bs[bk][bcol]      = b0;
        *(float4*)&Bs[bk][64 + bcol] = b1;
        __syncthreads();
#pragma unroll
        for (int k = 0; k < BK; ++k) {
            float4 a  = *(const float4*)&As[k][ty * 4];
            float4 p0 = *(const float4*)&Bs[k][tx * 4];
            float4 p1 = *(const float4*)&Bs[k][64 + tx * 4];
            float ar[4] = {a.x, a.y, a.z, a.w};
            float bc[8] = {p0.x, p0.y, p0.z, p0.w, p1.x, p1.y, p1.z, p1.w};
#pragma unroll
            for (int r = 0; r < 4; ++r)
#pragma unroll
                for (int c = 0; c < 8; ++c)
                    acc[r][c] += ar[r] * bc[c];
        }
    }
    float4 bl4 = *(const float4*)(bl + tx * 4);
    float4 br4 = *(const float4*)(br + tx * 4);
#pragma unroll
    for (int r = 0; r < 4; ++r) {
        int grow = row0 + ty * 4 + r;
        if (grow < n) {
            float4 ol, orr;
            ol.x = acc[r][0] + bl4.x; ol.y = acc[r][1] + bl4.y;
            ol.z = acc[r][2] + bl4.z; ol.w = acc[r][3] + bl4.w;
            orr.x = acc[r][4] + br4.x; orr.y = acc[r][5] + br4.y;
            orr.z = acc[r][6] + br4.z; orr.w = acc[r][7] + br4.w;
            *(float4*)(xl + (size_t)grow * HC + tx * 4) = ol;
            *(float4*)(xr + (size_t)grow * HC + tx * 4) = orr;
        }
    }
}

// ---------------- head GEMM: out = sigmoid(h @ Wo + bo) ----------------
// h:[n,64], Wo:[64,256]. tile 64 rows x 128 cols (gridDim.y=2), BK=16.
__global__ __launch_bounds__(256) void head_gemm_k(const float* __restrict__ h,
                                                   const float* __restrict__ Wo,
                                                   const float* __restrict__ bo,
                                                   float* __restrict__ out, int n) {
    __shared__ float As[BK][68];
    __shared__ float Bs[BK][128];
    int t = threadIdx.x;
    int tx = t & 15, ty = t >> 4;
    int row0 = blockIdx.x * 64;
    int coloff = blockIdx.y * 128;
    float acc[4][8] = {};
    int arow = t >> 2;
    int akb  = (t & 3) * 4;
    int bk   = t >> 4;
    int bcol = (t & 15) * 4;
    bool arow_ok = (row0 + arow) < n;
    const float* Aptr = h + (size_t)(row0 + arow) * HC + akb;

    for (int kc = 0; kc < HC; kc += BK) {
        float4 av = make_float4(0.f, 0.f, 0.f, 0.f);
        if (arow_ok) av = *(const float4*)(Aptr + kc);
        float4 b0 = *(const float4*)(Wo + (size_t)(kc + bk) * DIN + coloff + bcol);
        float4 b1 = *(const float4*)(Wo + (size_t)(kc + bk) * DIN + coloff + 64 + bcol);
        __syncthreads();
        As[akb + 0][arow] = av.x;
        As[akb + 1][arow] = av.y;
        As[akb + 2][arow] = av.z;
        As[akb + 3][arow] = av.w;
        *(float4*)&Bs[bk][bcol]      = b0;
        *(float4*)&Bs[bk][64 + bcol] = b1;
        __syncthreads();
#pragma unroll
        for (int k = 0; k < BK; ++k) {
            float4 a  = *(const float4*)&As[k][ty * 4];
            float4 p0 = *(const float4*)&Bs[k][tx * 4];
            float4 p1 = *(const float4*)&Bs[k][64 + tx * 4];
            float ar[4] = {a.x, a.y, a.z, a.w};
            float bc[8] = {p0.x, p0.y, p0.z, p0.w, p1.x, p1.y, p1.z, p1.w};
#pragma unroll
            for (int r = 0; r < 4; ++r)
#pragma unroll
                for (int c = 0; c < 8; ++c)
                    acc[r][c] += ar[r] * bc[c];
        }
    }
    float4 ba = *(const float4*)(bo + coloff + tx * 4);
    float4 bb = *(const float4*)(bo + coloff + 64 + tx * 4);
#pragma unroll
    for (int r = 0; r < 4; ++r) {
        int grow = row0 + ty * 4 + r;
        if (grow < n) {
            float4 o0, o1;
            o0.x = 1.f / (1.f + __expf(-(acc[r][0] + ba.x)));
            o0.y = 1.f / (1.f + __expf(-(acc[r][1] + ba.y)));
            o0.z = 1.f / (1.f + __expf(-(acc[r][2] + ba.z)));
            o0.w = 1.f / (1.f + __expf(-(acc[r][3] + ba.w)));
            o1.x = 1.f / (1.f + __expf(-(acc[r][4] + bb.x)));
            o1.y = 1.f / (1.f + __expf(-(acc[r][5] + bb.y)));
            o1.z = 1.f / (1.f + __expf(-(acc[r][6] + bb.z)));
            o1.w = 1.f / (1.f + __expf(-(acc[r][7] + bb.w)));
            *(float4*)(out + (size_t)grow * DIN + coloff + tx * 4)      = o0;
            *(float4*)(out + (size_t)grow * DIN + coloff + 64 + tx * 4) = o1;
        }
    }
}

// ---------------- edge aggregation (one wave per node, 4-edge ILP) ----------------
__global__ __launch_bounds__(256) void agg_k(const float* __restrict__ xl,
                                             const float* __restrict__ xr,
                                             const float* __restrict__ att,
                                             const float* __restrict__ bias,
                                             const int* __restrict__ offs,
                                             const int* __restrict__ ssrc,
                                             float* __restrict__ out, int n) {
    int wave = (blockIdx.x * 256 + threadIdx.x) >> 6;
    int lane = threadIdx.x & 63;
    if (wave >= n) return;
    float xrv = xr[(size_t)wave * HC + lane];
    float attv = att[lane];
    float acc = 0.f, den = 0.f;
    int lo = __builtin_amdgcn_readfirstlane(offs[wave]);
    int hi = __builtin_amdgcn_readfirstlane(offs[wave + 1]);
    int i = lo;
    for (; i + 4 <= hi; i += 4) {
        int j0 = ssrc[i], j1 = ssrc[i + 1], j2 = ssrc[i + 2], j3 = ssrc[i + 3];
        float x0 = xl[(size_t)j0 * HC + lane];
        float x1 = xl[(size_t)j1 * HC + lane];
        float x2 = xl[(size_t)j2 * HC + lane];
        float x3 = xl[(size_t)j3 * HC + lane];
        float s0 = x0 + xrv, s1 = x1 + xrv, s2 = x2 + xrv, s3 = x3 + xrv;
        float v0 = attv * (s0 > 0.f ? s0 : NEG * s0);
        float v1 = attv * (s1 > 0.f ? s1 : NEG * s1);
        float v2 = attv * (s2 > 0.f ? s2 : NEG * s2);
        float v3 = attv * (s3 > 0.f ? s3 : NEG * s3);
        v0 += __shfl_xor(v0, 1); v1 += __shfl_xor(v1, 1);
        v2 += __shfl_xor(v2, 1); v3 += __shfl_xor(v3, 1);
        v0 += __shfl_xor(v0, 2); v1 += __shfl_xor(v1, 2);
        v2 += __shfl_xor(v2, 2); v3 += __shfl_xor(v3, 2);
        v0 += __shfl_xor(v0, 4); v1 += __shfl_xor(v1, 4);
        v2 += __shfl_xor(v2, 4); v3 += __shfl_xor(v3, 4);
        v0 += __shfl_xor(v0, 8); v1 += __shfl_xor(v1, 8);
        v2 += __shfl_xor(v2, 8); v3 += __shfl_xor(v3, 8);
        float e0 = __expf(v0), e1 = __expf(v1), e2 = __expf(v2), e3 = __expf(v3);
        den += (e0 + e1) + (e2 + e3);
        acc += e0 * x0; acc += e1 * x1; acc += e2 * x2; acc += e3 * x3;
    }
    for (; i < hi; ++i) {
        int j = ssrc[i];
        float xlv = xl[(size_t)j * HC + lane];
        float s = xlv + xrv;
        float lr = s > 0.f ? s : NEG * s;
        float v = attv * lr;
        v += __shfl_xor(v, 1);
        v += __shfl_xor(v, 2);
        v += __shfl_xor(v, 4);
        v += __shfl_xor(v, 8);
        float ex = __expf(v);
        den += ex;
        acc += ex * xlv;
    }
    float o = (den > 0.f) ? acc / den : 0.f;
    o += bias[lane];
    out[(size_t)wave * HC + lane] = fmaxf(o, 0.f);
}

extern "C" void kernel_launch(void* const* d_in, const int* in_sizes, int n_in,
                              void* d_out, int out_size, void* d_ws, size_t ws_size,
                              hipStream_t stream) {
    const float* x    = (const float*)d_in[0];
    const int*   ei   = (const int*)d_in[1];
    const float* Wl1  = (const float*)d_in[2];
    const float* bl1  = (const float*)d_in[3];
    const float* Wr1  = (const float*)d_in[4];
    const float* br1  = (const float*)d_in[5];
    const float* att1 = (const float*)d_in[6];
    const float* bias1= (const float*)d_in[7];
    const float* Wl2  = (const float*)d_in[8];
    const float* bl2  = (const float*)d_in[9];
    const float* Wr2  = (const float*)d_in[10];
    const float* br2  = (const float*)d_in[11];
    const float* att2 = (const float*)d_in[12];
    const float* bias2= (const float*)d_in[13];
    const float* Wo   = (const float*)d_in[14];
    const float* bo   = (const float*)d_in[15];
    float* out = (float*)d_out;

    int E = in_sizes[1] / 2;
    const int* srcv = ei;
    const int* dstv = ei + E;

    size_t NF = (size_t)NN * HC;
    float* xl = (float*)d_ws;
    float* xr = xl + NF;
    float* hb = xr + NF;                  // h1, later h2
    int* counts = (int*)(hb + NF);
    int* offs   = counts + NN;            // NN+1 entries
    int* cursor = offs + NN + 1;
    int* ssrc   = cursor + NN;            // E entries
    int* bsum   = ssrc + E;               // scan block sums

    int nb = (NN + 1023) / 1024;

    hipMemsetAsync(counts, 0, NN * sizeof(int), stream);
    hist_k<<<(E + 255) / 256, 256, 0, stream>>>(dstv, counts, E);
    scan1_k<<<nb, 256, 0, stream>>>(counts, bsum, NN);
    scan2_k<<<1, 64, 0, stream>>>(bsum, offs, nb, NN);
    scan3_k<<<nb, 256, 0, stream>>>(counts, bsum, offs, cursor, NN);
    scatter_k<<<(E + 255) / 256, 256, 0, stream>>>(srcv, dstv, cursor, ssrc, E);

    int gb = (NN + 63) / 64;
    // layer 1
    gemm_dual_k<<<gb, 256, 0, stream>>>(x, Wl1, bl1, Wr1, br1, xl, xr, NN, DIN);
    agg_k<<<(NN + 3) / 4, 256, 0, stream>>>(xl, xr, att1, bias1, offs, ssrc, hb, NN);
    // layer 2
    gemm_dual_k<<<gb, 256, 0, stream>>>(hb, Wl2, bl2, Wr2, br2, xl, xr, NN, HC);
    agg_k<<<(NN + 3) / 4, 256, 0, stream>>>(xl, xr, att2, bias2, offs, ssrc, hb, NN);
    // head
    head_gemm_k<<<dim3(gb, 2), 256, 0, stream>>>(hb, Wo, bo, out, NN);
}

// Round 4
// 422.559 us; speedup vs baseline: 2.2420x; 1.3233x over previous
//
#include <hip/hip_runtime.h>
#include <math.h>

#define NN 50000
#define DIN 256
#define HC 64
#define NEG 0.2f
#define BK 16
#define NB 196          // ceil(NN/256) coarse buckets (dst >> 8)
#define EPB 4096        // edges per bin_k block
#define CAP 36864       // bsort LDS staging capacity (expected bucket ~8192)

// ---------------- CSR build: bucketed counting sort ----------------

// coarse histogram over NB buckets, LDS-aggregated
__global__ __launch_bounds__(256) void bhist_k(const int* __restrict__ dst,
                                               int* __restrict__ bcnt, int E) {
    __shared__ int h[NB];
    int t = threadIdx.x;
    for (int i = t; i < NB; i += 256) h[i] = 0;
    __syncthreads();
    int base = blockIdx.x * 2048 + t;
#pragma unroll
    for (int k = 0; k < 8; ++k) {
        int e = base + k * 256;
        if (e < E) atomicAdd(&h[dst[e] >> 8], 1);
    }
    __syncthreads();
    for (int i = t; i < NB; i += 256)
        if (h[i]) atomicAdd(&bcnt[i], h[i]);
}

// single-block scan of NB bucket counts -> boffs[NB+1], bcursor; offs[NN]=E
__global__ __launch_bounds__(256) void bscan_k(const int* __restrict__ bcnt,
                                               int* __restrict__ boffs,
                                               int* __restrict__ bcursor,
                                               int* __restrict__ offs, int E) {
    __shared__ int s[256];
    int t = threadIdx.x;
    s[t] = (t < NB) ? bcnt[t] : 0;
    __syncthreads();
    for (int off = 1; off < 256; off <<= 1) {
        int v = s[t];
        int u = (t >= off) ? s[t - off] : 0;
        __syncthreads();
        s[t] = v + u;
        __syncthreads();
    }
    if (t < NB) {
        int ex = (t == 0) ? 0 : s[t - 1];
        boffs[t] = ex;
        bcursor[t] = ex;
    }
    if (t == NB) boffs[NB] = s[NB - 1];
    if (t == 0) offs[NN] = E;
}

// bin edges into bucket-contiguous regions of epair (packed src<<8 | dst&255),
// locally sorted by bucket in LDS so global writes are coalesced runs.
__global__ __launch_bounds__(1024) void bin_k(const int* __restrict__ src,
                                              const int* __restrict__ dst,
                                              int* __restrict__ bcursor,
                                              unsigned* __restrict__ epair, int E) {
    __shared__ int hist[NB];
    __shared__ int lofs[NB];
    __shared__ int gshift[NB];
    __shared__ int scanb[256];
    __shared__ unsigned pbuf[EPB];
    __shared__ unsigned char abkt[EPB];
    int t = threadIdx.x;
    for (int i = t; i < NB; i += 1024) hist[i] = 0;
    __syncthreads();
    int e0 = blockIdx.x * EPB;
    unsigned p[4]; int bk[4], rk[4]; bool val[4];
#pragma unroll
    for (int k = 0; k < 4; ++k) {
        int e = e0 + k * 1024 + t;
        val[k] = e < E;
        if (val[k]) {
            int s = src[e], d = dst[e];
            p[k] = ((unsigned)s << 8) | (unsigned)(d & 255);
            bk[k] = d >> 8;
            rk[k] = atomicAdd(&hist[bk[k]], 1);
        }
    }
    __syncthreads();
    if (t < 256) scanb[t] = (t < NB) ? hist[t] : 0;
    __syncthreads();
    for (int off = 1; off < 256; off <<= 1) {
        int v = 0, u = 0;
        if (t < 256) { v = scanb[t]; if (t >= off) u = scanb[t - off]; }
        __syncthreads();
        if (t < 256) scanb[t] = v + u;
        __syncthreads();
    }
    if (t < NB) {
        int ex = (t == 0) ? 0 : scanb[t - 1];
        lofs[t] = ex;
        int gb = atomicAdd(&bcursor[t], hist[t]);
        gshift[t] = gb - ex;
    }
    __syncthreads();
    int total = scanb[NB - 1];
#pragma unroll
    for (int k = 0; k < 4; ++k) {
        if (val[k]) {
            int pos = lofs[bk[k]] + rk[k];
            pbuf[pos] = p[k];
            abkt[pos] = (unsigned char)bk[k];
        }
    }
    __syncthreads();
    for (int i = t; i < total; i += 1024) {
        int b = abkt[i];
        epair[gshift[b] + i] = pbuf[i];
    }
}

// per-bucket exact counting sort in LDS: emits offs + ssrc (coalesced flush)
__global__ __launch_bounds__(1024) void bsort_k(const unsigned* __restrict__ epair,
                                                const int* __restrict__ boffs,
                                                int* __restrict__ offs,
                                                int* __restrict__ ssrc, int n) {
    __shared__ int lhist[256];
    __shared__ int lcur[256];
    __shared__ int scanb[256];
    __shared__ int sbuf[CAP];
    int b = blockIdx.x, t = threadIdx.x;
    int start = boffs[b], end = boffs[b + 1];
    int cnt = end - start;
    if (t < 256) lhist[t] = 0;
    __syncthreads();
    for (int i = t; i < cnt; i += 1024) {
        unsigned p = epair[start + i];
        atomicAdd(&lhist[p & 255], 1);
    }
    __syncthreads();
    if (t < 256) scanb[t] = lhist[t];
    __syncthreads();
    for (int off = 1; off < 256; off <<= 1) {
        int v = 0, u = 0;
        if (t < 256) { v = scanb[t]; if (t >= off) u = scanb[t - off]; }
        __syncthreads();
        if (t < 256) scanb[t] = v + u;
        __syncthreads();
    }
    if (t < 256) {
        int ex = (t == 0) ? 0 : scanb[t - 1];
        lcur[t] = ex;
        int node = b * 256 + t;
        if (node < n) offs[node] = start + ex;
    }
    __syncthreads();
    if (cnt <= CAP) {
        for (int i = t; i < cnt; i += 1024) {
            unsigned p = epair[start + i];
            int r = atomicAdd(&lcur[p & 255], 1);
            sbuf[r] = (int)(p >> 8);
        }
        __syncthreads();
        for (int i = t; i < cnt; i += 1024) ssrc[start + i] = sbuf[i];
    } else {  // fallback (never expected for random graphs)
        for (int i = t; i < cnt; i += 1024) {
            unsigned p = epair[start + i];
            int r = atomicAdd(&lcur[p & 255], 1);
            ssrc[start + r] = (int)(p >> 8);
        }
    }
}

// ---------------- tiled dual GEMM: [xl|xr] = A @ [Wl|Wr] + [bl|br] ----------------
// tile 64 rows x 128 cols, BK=16. Each thread: 4 rows x 8 cols.
__global__ __launch_bounds__(256) void gemm_dual_k(const float* __restrict__ A,
                                                   const float* __restrict__ Wl,
                                                   const float* __restrict__ bl,
                                                   const float* __restrict__ Wr,
                                                   const float* __restrict__ br,
                                                   float* __restrict__ xl,
                                                   float* __restrict__ xr,
                                                   int n, int K) {
    __shared__ float As[BK][68];   // transposed, +4 pad -> 2-way (free) staging writes
    __shared__ float Bs[BK][128];
    int t = threadIdx.x;
    int tx = t & 15, ty = t >> 4;
    int row0 = blockIdx.x * 64;
    float acc[4][8] = {};
    int arow = t >> 2;             // 0..63
    int akb  = (t & 3) * 4;        // 0,4,8,12
    int bk   = t >> 4;             // 0..15
    int bcol = (t & 15) * 4;       // 0..60
    bool arow_ok = (row0 + arow) < n;
    const float* Aptr = A + (size_t)(row0 + arow) * K + akb;

    for (int kc = 0; kc < K; kc += BK) {
        float4 av = make_float4(0.f, 0.f, 0.f, 0.f);
        if (arow_ok) av = *(const float4*)(Aptr + kc);
        float4 b0 = *(const float4*)(Wl + (size_t)(kc + bk) * HC + bcol);
        float4 b1 = *(const float4*)(Wr + (size_t)(kc + bk) * HC + bcol);
        __syncthreads();
        As[akb + 0][arow] = av.x;
        As[akb + 1][arow] = av.y;
        As[akb + 2][arow] = av.z;
        As[akb + 3][arow] = av.w;
        *(float4*)&Bs[bk][bcol]      = b0;
        *(float4*)&Bs[bk][64 + bcol] = b1;
        __syncthreads();
#pragma unroll
        for (int k = 0; k < BK; ++k) {
            float4 a  = *(const float4*)&As[k][ty * 4];
            float4 p0 = *(const float4*)&Bs[k][tx * 4];
            float4 p1 = *(const float4*)&Bs[k][64 + tx * 4];
            float ar[4] = {a.x, a.y, a.z, a.w};
            float bc[8] = {p0.x, p0.y, p0.z, p0.w, p1.x, p1.y, p1.z, p1.w};
#pragma unroll
            for (int r = 0; r < 4; ++r)
#pragma unroll
                for (int c = 0; c < 8; ++c)
                    acc[r][c] += ar[r] * bc[c];
        }
    }
    float4 bl4 = *(const float4*)(bl + tx * 4);
    float4 br4 = *(const float4*)(br + tx * 4);
#pragma unroll
    for (int r = 0; r < 4; ++r) {
        int grow = row0 + ty * 4 + r;
        if (grow < n) {
            float4 ol, orr;
            ol.x = acc[r][0] + bl4.x; ol.y = acc[r][1] + bl4.y;
            ol.z = acc[r][2] + bl4.z; ol.w = acc[r][3] + bl4.w;
            orr.x = acc[r][4] + br4.x; orr.y = acc[r][5] + br4.y;
            orr.z = acc[r][6] + br4.z; orr.w = acc[r][7] + br4.w;
            *(float4*)(xl + (size_t)grow * HC + tx * 4) = ol;
            *(float4*)(xr + (size_t)grow * HC + tx * 4) = orr;
        }
    }
}

// ---------------- head GEMM: out = sigmoid(h @ Wo + bo) ----------------
__global__ __launch_bounds__(256) void head_gemm_k(const float* __restrict__ h,
                                                   const float* __restrict__ Wo,
                                                   const float* __restrict__ bo,
                                                   float* __restrict__ out, int n) {
    __shared__ float As[BK][68];
    __shared__ float Bs[BK][128];
    int t = threadIdx.x;
    int tx = t & 15, ty = t >> 4;
    int row0 = blockIdx.x * 64;
    int coloff = blockIdx.y * 128;
    float acc[4][8] = {};
    int arow = t >> 2;
    int akb  = (t & 3) * 4;
    int bk   = t >> 4;
    int bcol = (t & 15) * 4;
    bool arow_ok = (row0 + arow) < n;
    const float* Aptr = h + (size_t)(row0 + arow) * HC + akb;

    for (int kc = 0; kc < HC; kc += BK) {
        float4 av = make_float4(0.f, 0.f, 0.f, 0.f);
        if (arow_ok) av = *(const float4*)(Aptr + kc);
        float4 b0 = *(const float4*)(Wo + (size_t)(kc + bk) * DIN + coloff + bcol);
        float4 b1 = *(const float4*)(Wo + (size_t)(kc + bk) * DIN + coloff + 64 + bcol);
        __syncthreads();
        As[akb + 0][arow] = av.x;
        As[akb + 1][arow] = av.y;
        As[akb + 2][arow] = av.z;
        As[akb + 3][arow] = av.w;
        *(float4*)&Bs[bk][bcol]      = b0;
        *(float4*)&Bs[bk][64 + bcol] = b1;
        __syncthreads();
#pragma unroll
        for (int k = 0; k < BK; ++k) {
            float4 a  = *(const float4*)&As[k][ty * 4];
            float4 p0 = *(const float4*)&Bs[k][tx * 4];
            float4 p1 = *(const float4*)&Bs[k][64 + tx * 4];
            float ar[4] = {a.x, a.y, a.z, a.w};
            float bc[8] = {p0.x, p0.y, p0.z, p0.w, p1.x, p1.y, p1.z, p1.w};
#pragma unroll
            for (int r = 0; r < 4; ++r)
#pragma unroll
                for (int c = 0; c < 8; ++c)
                    acc[r][c] += ar[r] * bc[c];
        }
    }
    float4 ba = *(const float4*)(bo + coloff + tx * 4);
    float4 bb = *(const float4*)(bo + coloff + 64 + tx * 4);
#pragma unroll
    for (int r = 0; r < 4; ++r) {
        int grow = row0 + ty * 4 + r;
        if (grow < n) {
            float4 o0, o1;
            o0.x = 1.f / (1.f + __expf(-(acc[r][0] + ba.x)));
            o0.y = 1.f / (1.f + __expf(-(acc[r][1] + ba.y)));
            o0.z = 1.f / (1.f + __expf(-(acc[r][2] + ba.z)));
            o0.w = 1.f / (1.f + __expf(-(acc[r][3] + ba.w)));
            o1.x = 1.f / (1.f + __expf(-(acc[r][4] + bb.x)));
            o1.y = 1.f / (1.f + __expf(-(acc[r][5] + bb.y)));
            o1.z = 1.f / (1.f + __expf(-(acc[r][6] + bb.z)));
            o1.w = 1.f / (1.f + __expf(-(acc[r][7] + bb.w)));
            *(float4*)(out + (size_t)grow * DIN + coloff + tx * 4)      = o0;
            *(float4*)(out + (size_t)grow * DIN + coloff + 64 + tx * 4) = o1;
        }
    }
}

// ---------------- edge aggregation (one wave per node, 4-edge ILP) ----------------
__global__ __launch_bounds__(256) void agg_k(const float* __restrict__ xl,
                                             const float* __restrict__ xr,
                                             const float* __restrict__ att,
                                             const float* __restrict__ bias,
                                             const int* __restrict__ offs,
                                             const int* __restrict__ ssrc,
                                             float* __restrict__ out, int n) {
    int wave = (blockIdx.x * 256 + threadIdx.x) >> 6;
    int lane = threadIdx.x & 63;
    if (wave >= n) return;
    float xrv = xr[(size_t)wave * HC + lane];
    float attv = att[lane];
    float acc = 0.f, den = 0.f;
    int lo = __builtin_amdgcn_readfirstlane(offs[wave]);
    int hi = __builtin_amdgcn_readfirstlane(offs[wave + 1]);
    int i = lo;
    for (; i + 4 <= hi; i += 4) {
        int j0 = ssrc[i], j1 = ssrc[i + 1], j2 = ssrc[i + 2], j3 = ssrc[i + 3];
        float x0 = xl[(size_t)j0 * HC + lane];
        float x1 = xl[(size_t)j1 * HC + lane];
        float x2 = xl[(size_t)j2 * HC + lane];
        float x3 = xl[(size_t)j3 * HC + lane];
        float s0 = x0 + xrv, s1 = x1 + xrv, s2 = x2 + xrv, s3 = x3 + xrv;
        float v0 = attv * (s0 > 0.f ? s0 : NEG * s0);
        float v1 = attv * (s1 > 0.f ? s1 : NEG * s1);
        float v2 = attv * (s2 > 0.f ? s2 : NEG * s2);
        float v3 = attv * (s3 > 0.f ? s3 : NEG * s3);
        v0 += __shfl_xor(v0, 1); v1 += __shfl_xor(v1, 1);
        v2 += __shfl_xor(v2, 1); v3 += __shfl_xor(v3, 1);
        v0 += __shfl_xor(v0, 2); v1 += __shfl_xor(v1, 2);
        v2 += __shfl_xor(v2, 2); v3 += __shfl_xor(v3, 2);
        v0 += __shfl_xor(v0, 4); v1 += __shfl_xor(v1, 4);
        v2 += __shfl_xor(v2, 4); v3 += __shfl_xor(v3, 4);
        v0 += __shfl_xor(v0, 8); v1 += __shfl_xor(v1, 8);
        v2 += __shfl_xor(v2, 8); v3 += __shfl_xor(v3, 8);
        float e0 = __expf(v0), e1 = __expf(v1), e2 = __expf(v2), e3 = __expf(v3);
        den += (e0 + e1) + (e2 + e3);
        acc += e0 * x0; acc += e1 * x1; acc += e2 * x2; acc += e3 * x3;
    }
    for (; i < hi; ++i) {
        int j = ssrc[i];
        float xlv = xl[(size_t)j * HC + lane];
        float s = xlv + xrv;
        float lr = s > 0.f ? s : NEG * s;
        float v = attv * lr;
        v += __shfl_xor(v, 1);
        v += __shfl_xor(v, 2);
        v += __shfl_xor(v, 4);
        v += __shfl_xor(v, 8);
        float ex = __expf(v);
        den += ex;
        acc += ex * xlv;
    }
    float o = (den > 0.f) ? acc / den : 0.f;
    o += bias[lane];
    out[(size_t)wave * HC + lane] = fmaxf(o, 0.f);
}

extern "C" void kernel_launch(void* const* d_in, const int* in_sizes, int n_in,
                              void* d_out, int out_size, void* d_ws, size_t ws_size,
                              hipStream_t stream) {
    const float* x    = (const float*)d_in[0];
    const int*   ei   = (const int*)d_in[1];
    const float* Wl1  = (const float*)d_in[2];
    const float* bl1  = (const float*)d_in[3];
    const float* Wr1  = (const float*)d_in[4];
    const float* br1  = (const float*)d_in[5];
    const float* att1 = (const float*)d_in[6];
    const float* bias1= (const float*)d_in[7];
    const float* Wl2  = (const float*)d_in[8];
    const float* bl2  = (const float*)d_in[9];
    const float* Wr2  = (const float*)d_in[10];
    const float* br2  = (const float*)d_in[11];
    const float* att2 = (const float*)d_in[12];
    const float* bias2= (const float*)d_in[13];
    const float* Wo   = (const float*)d_in[14];
    const float* bo   = (const float*)d_in[15];
    float* out = (float*)d_out;

    int E = in_sizes[1] / 2;
    const int* srcv = ei;
    const int* dstv = ei + E;

    size_t NF = (size_t)NN * HC;
    float* xl = (float*)d_ws;
    float* xr = xl + NF;
    float* hb = xr + NF;                  // h1, later h2
    int* offs    = (int*)(hb + NF);       // NN+1
    int* ssrc    = offs + NN + 1;         // E
    int* boffs   = ssrc + E;              // NB+1
    int* bcursor = boffs + NB + 1;        // NB
    int* bcnt    = bcursor + NB;          // NB
    // epair scratch lives in d_out (6.4 MB of 51.2 MB), fully consumed
    // before head_gemm_k writes out.
    unsigned* epair = (unsigned*)d_out;

    hipMemsetAsync(bcnt, 0, NB * sizeof(int), stream);
    bhist_k<<<(E + 2047) / 2048, 256, 0, stream>>>(dstv, bcnt, E);
    bscan_k<<<1, 256, 0, stream>>>(bcnt, boffs, bcursor, offs, E);
    bin_k<<<(E + EPB - 1) / EPB, 1024, 0, stream>>>(srcv, dstv, bcursor, epair, E);
    bsort_k<<<NB, 1024, 0, stream>>>(epair, boffs, offs, ssrc, NN);

    int gb = (NN + 63) / 64;
    // layer 1
    gemm_dual_k<<<gb, 256, 0, stream>>>(x, Wl1, bl1, Wr1, br1, xl, xr, NN, DIN);
    agg_k<<<(NN + 3) / 4, 256, 0, stream>>>(xl, xr, att1, bias1, offs, ssrc, hb, NN);
    // layer 2
    gemm_dual_k<<<gb, 256, 0, stream>>>(hb, Wl2, bl2, Wr2, br2, xl, xr, NN, HC);
    agg_k<<<(NN + 3) / 4, 256, 0, stream>>>(xl, xr, att2, bias2, offs, ssrc, hb, NN);
    // head
    head_gemm_k<<<dim3(gb, 2), 256, 0, stream>>>(hb, Wo, bo, out, NN);
}

// Round 5
// 384.058 us; speedup vs baseline: 2.4668x; 1.1002x over previous
//
#include <hip/hip_runtime.h>
#include <math.h>

#define NN 50000
#define DIN 256
#define HC 64
#define NEG 0.2f
#define BK 16
#define GM 128          // gemm rows per block
#define NB 196          // ceil(NN/256) coarse buckets (dst >> 8)
#define EPB 4096        // edges per bin_k block
#define CAP 36864       // bsort LDS staging capacity (expected bucket ~8192)

// ---- DPP 16-lane reduce+broadcast (quad xor1, xor2, half-mirror, mirror) ----
template <int CTRL>
__device__ __forceinline__ float dpp_mov(float x) {
    int r = __builtin_amdgcn_update_dpp(0, __float_as_int(x), CTRL, 0xF, 0xF, true);
    return __int_as_float(r);
}
__device__ __forceinline__ float reduce16_bcast(float v) {
    v += dpp_mov<0xB1>(v);    // quad_perm [1,0,3,2]  : xor 1
    v += dpp_mov<0x4E>(v);    // quad_perm [2,3,0,1]  : xor 2
    v += dpp_mov<0x141>(v);   // row_half_mirror      : xor 7 (== xor 4 on quad sums)
    v += dpp_mov<0x140>(v);   // row_mirror           : xor 15 (== xor 8)
    return v;
}

// ---------------- CSR build: bucketed counting sort ----------------

__global__ __launch_bounds__(256) void bhist_k(const int* __restrict__ dst,
                                               int* __restrict__ bcnt, int E) {
    __shared__ int h[NB];
    int t = threadIdx.x;
    for (int i = t; i < NB; i += 256) h[i] = 0;
    __syncthreads();
    int base = blockIdx.x * 2048 + t;
#pragma unroll
    for (int k = 0; k < 8; ++k) {
        int e = base + k * 256;
        if (e < E) atomicAdd(&h[dst[e] >> 8], 1);
    }
    __syncthreads();
    for (int i = t; i < NB; i += 256)
        if (h[i]) atomicAdd(&bcnt[i], h[i]);
}

__global__ __launch_bounds__(256) void bscan_k(const int* __restrict__ bcnt,
                                               int* __restrict__ boffs,
                                               int* __restrict__ bcursor,
                                               int* __restrict__ offs, int E) {
    __shared__ int s[256];
    int t = threadIdx.x;
    s[t] = (t < NB) ? bcnt[t] : 0;
    __syncthreads();
    for (int off = 1; off < 256; off <<= 1) {
        int v = s[t];
        int u = (t >= off) ? s[t - off] : 0;
        __syncthreads();
        s[t] = v + u;
        __syncthreads();
    }
    if (t < NB) {
        int ex = (t == 0) ? 0 : s[t - 1];
        boffs[t] = ex;
        bcursor[t] = ex;
    }
    if (t == NB) boffs[NB] = s[NB - 1];
    if (t == 0) offs[NN] = E;
}

__global__ __launch_bounds__(1024) void bin_k(const int* __restrict__ src,
                                              const int* __restrict__ dst,
                                              int* __restrict__ bcursor,
                                              unsigned* __restrict__ epair, int E) {
    __shared__ int hist[NB];
    __shared__ int lofs[NB];
    __shared__ int gshift[NB];
    __shared__ int scanb[256];
    __shared__ unsigned pbuf[EPB];
    __shared__ unsigned char abkt[EPB];
    int t = threadIdx.x;
    for (int i = t; i < NB; i += 1024) hist[i] = 0;
    __syncthreads();
    int e0 = blockIdx.x * EPB;
    unsigned p[4]; int bk[4], rk[4]; bool val[4];
#pragma unroll
    for (int k = 0; k < 4; ++k) {
        int e = e0 + k * 1024 + t;
        val[k] = e < E;
        if (val[k]) {
            int s = src[e], d = dst[e];
            p[k] = ((unsigned)s << 8) | (unsigned)(d & 255);
            bk[k] = d >> 8;
            rk[k] = atomicAdd(&hist[bk[k]], 1);
        }
    }
    __syncthreads();
    if (t < 256) scanb[t] = (t < NB) ? hist[t] : 0;
    __syncthreads();
    for (int off = 1; off < 256; off <<= 1) {
        int v = 0, u = 0;
        if (t < 256) { v = scanb[t]; if (t >= off) u = scanb[t - off]; }
        __syncthreads();
        if (t < 256) scanb[t] = v + u;
        __syncthreads();
    }
    if (t < NB) {
        int ex = (t == 0) ? 0 : scanb[t - 1];
        lofs[t] = ex;
        int gb = atomicAdd(&bcursor[t], hist[t]);
        gshift[t] = gb - ex;
    }
    __syncthreads();
    int total = scanb[NB - 1];
#pragma unroll
    for (int k = 0; k < 4; ++k) {
        if (val[k]) {
            int pos = lofs[bk[k]] + rk[k];
            pbuf[pos] = p[k];
            abkt[pos] = (unsigned char)bk[k];
        }
    }
    __syncthreads();
    for (int i = t; i < total; i += 1024) {
        int b = abkt[i];
        epair[gshift[b] + i] = pbuf[i];
    }
}

// per-bucket counting sort; ssrc holds BYTE offsets (src*HC*4 == src<<8)
__global__ __launch_bounds__(1024) void bsort_k(const unsigned* __restrict__ epair,
                                                const int* __restrict__ boffs,
                                                int* __restrict__ offs,
                                                unsigned* __restrict__ ssrc, int n) {
    __shared__ int lhist[256];
    __shared__ int lcur[256];
    __shared__ int scanb[256];
    __shared__ unsigned sbuf[CAP];
    int b = blockIdx.x, t = threadIdx.x;
    int start = boffs[b], end = boffs[b + 1];
    int cnt = end - start;
    if (t < 256) lhist[t] = 0;
    __syncthreads();
    for (int i = t; i < cnt; i += 1024) {
        unsigned p = epair[start + i];
        atomicAdd(&lhist[p & 255], 1);
    }
    __syncthreads();
    if (t < 256) scanb[t] = lhist[t];
    __syncthreads();
    for (int off = 1; off < 256; off <<= 1) {
        int v = 0, u = 0;
        if (t < 256) { v = scanb[t]; if (t >= off) u = scanb[t - off]; }
        __syncthreads();
        if (t < 256) scanb[t] = v + u;
        __syncthreads();
    }
    if (t < 256) {
        int ex = (t == 0) ? 0 : scanb[t - 1];
        lcur[t] = ex;
        int node = b * 256 + t;
        if (node < n) offs[node] = start + ex;
    }
    __syncthreads();
    if (cnt <= CAP) {
        for (int i = t; i < cnt; i += 1024) {
            unsigned p = epair[start + i];
            int r = atomicAdd(&lcur[p & 255], 1);
            sbuf[r] = p & ~255u;           // src<<8 = byte offset into xl
        }
        __syncthreads();
        for (int i = t; i < cnt; i += 1024) ssrc[start + i] = sbuf[i];
    } else {
        for (int i = t; i < cnt; i += 1024) {
            unsigned p = epair[start + i];
            int r = atomicAdd(&lcur[p & 255], 1);
            ssrc[start + r] = p & ~255u;
        }
    }
}

// ---------------- tiled dual GEMM: [xl|xr] = A @ [Wl|Wr] + [bl|br] ----------------
// tile 128 rows x 128 cols, BK=16; each thread 8 rows x (4+4) cols.
__global__ __launch_bounds__(256) void gemm_dual_k(const float* __restrict__ A,
                                                   const float* __restrict__ Wl,
                                                   const float* __restrict__ bl,
                                                   const float* __restrict__ Wr,
                                                   const float* __restrict__ br,
                                                   float* __restrict__ xl,
                                                   float* __restrict__ xr,
                                                   int n, int K) {
    __shared__ float As[BK][GM + 4];
    __shared__ float Bs[BK][128];
    int t = threadIdx.x;
    int tx = t & 15, ty = t >> 4;
    int row0 = blockIdx.x * GM;
    float acc[8][8] = {};
    int arow = t >> 1;             // 0..127
    int akb  = (t & 1) * 8;        // 0 or 8
    int bk   = t >> 4;             // 0..15
    int bcol = (t & 15) * 4;       // 0..60
    bool arow_ok = (row0 + arow) < n;
    const float* Aptr = A + (size_t)(row0 + arow) * K + akb;

    for (int kc = 0; kc < K; kc += BK) {
        float4 av0 = make_float4(0.f, 0.f, 0.f, 0.f);
        float4 av1 = make_float4(0.f, 0.f, 0.f, 0.f);
        if (arow_ok) {
            av0 = *(const float4*)(Aptr + kc);
            av1 = *(const float4*)(Aptr + kc + 4);
        }
        float4 b0 = *(const float4*)(Wl + (size_t)(kc + bk) * HC + bcol);
        float4 b1 = *(const float4*)(Wr + (size_t)(kc + bk) * HC + bcol);
        __syncthreads();
        As[akb + 0][arow] = av0.x;
        As[akb + 1][arow] = av0.y;
        As[akb + 2][arow] = av0.z;
        As[akb + 3][arow] = av0.w;
        As[akb + 4][arow] = av1.x;
        As[akb + 5][arow] = av1.y;
        As[akb + 6][arow] = av1.z;
        As[akb + 7][arow] = av1.w;
        *(float4*)&Bs[bk][bcol]      = b0;
        *(float4*)&Bs[bk][64 + bcol] = b1;
        __syncthreads();
#pragma unroll
        for (int k = 0; k < BK; ++k) {
            float4 a0 = *(const float4*)&As[k][ty * 8];
            float4 a1 = *(const float4*)&As[k][ty * 8 + 4];
            float4 p0 = *(const float4*)&Bs[k][tx * 4];
            float4 p1 = *(const float4*)&Bs[k][64 + tx * 4];
            float ar[8] = {a0.x, a0.y, a0.z, a0.w, a1.x, a1.y, a1.z, a1.w};
            float bc[8] = {p0.x, p0.y, p0.z, p0.w, p1.x, p1.y, p1.z, p1.w};
#pragma unroll
            for (int r = 0; r < 8; ++r)
#pragma unroll
                for (int c = 0; c < 8; ++c)
                    acc[r][c] += ar[r] * bc[c];
        }
    }
    float4 bl4 = *(const float4*)(bl + tx * 4);
    float4 br4 = *(const float4*)(br + tx * 4);
#pragma unroll
    for (int r = 0; r < 8; ++r) {
        int grow = row0 + ty * 8 + r;
        if (grow < n) {
            float4 ol, orr;
            ol.x = acc[r][0] + bl4.x; ol.y = acc[r][1] + bl4.y;
            ol.z = acc[r][2] + bl4.z; ol.w = acc[r][3] + bl4.w;
            orr.x = acc[r][4] + br4.x; orr.y = acc[r][5] + br4.y;
            orr.z = acc[r][6] + br4.z; orr.w = acc[r][7] + br4.w;
            *(float4*)(xl + (size_t)grow * HC + tx * 4) = ol;
            *(float4*)(xr + (size_t)grow * HC + tx * 4) = orr;
        }
    }
}

// ---------------- head GEMM: out = sigmoid(h @ Wo + bo) ----------------
// tile 128 rows x 128 cols (gridDim.y = 2 for the 256 out cols)
__global__ __launch_bounds__(256) void head_gemm_k(const float* __restrict__ h,
                                                   const float* __restrict__ Wo,
                                                   const float* __restrict__ bo,
                                                   float* __restrict__ out, int n) {
    __shared__ float As[BK][GM + 4];
    __shared__ float Bs[BK][128];
    int t = threadIdx.x;
    int tx = t & 15, ty = t >> 4;
    int row0 = blockIdx.x * GM;
    int coloff = blockIdx.y * 128;
    float acc[8][8] = {};
    int arow = t >> 1;
    int akb  = (t & 1) * 8;
    int bk   = t >> 4;
    int bcol = (t & 15) * 4;
    bool arow_ok = (row0 + arow) < n;
    const float* Aptr = h + (size_t)(row0 + arow) * HC + akb;

    for (int kc = 0; kc < HC; kc += BK) {
        float4 av0 = make_float4(0.f, 0.f, 0.f, 0.f);
        float4 av1 = make_float4(0.f, 0.f, 0.f, 0.f);
        if (arow_ok) {
            av0 = *(const float4*)(Aptr + kc);
            av1 = *(const float4*)(Aptr + kc + 4);
        }
        float4 b0 = *(const float4*)(Wo + (size_t)(kc + bk) * DIN + coloff + bcol);
        float4 b1 = *(const float4*)(Wo + (size_t)(kc + bk) * DIN + coloff + 64 + bcol);
        __syncthreads();
        As[akb + 0][arow] = av0.x;
        As[akb + 1][arow] = av0.y;
        As[akb + 2][arow] = av0.z;
        As[akb + 3][arow] = av0.w;
        As[akb + 4][arow] = av1.x;
        As[akb + 5][arow] = av1.y;
        As[akb + 6][arow] = av1.z;
        As[akb + 7][arow] = av1.w;
        *(float4*)&Bs[bk][bcol]      = b0;
        *(float4*)&Bs[bk][64 + bcol] = b1;
        __syncthreads();
#pragma unroll
        for (int k = 0; k < BK; ++k) {
            float4 a0 = *(const float4*)&As[k][ty * 8];
            float4 a1 = *(const float4*)&As[k][ty * 8 + 4];
            float4 p0 = *(const float4*)&Bs[k][tx * 4];
            float4 p1 = *(const float4*)&Bs[k][64 + tx * 4];
            float ar[8] = {a0.x, a0.y, a0.z, a0.w, a1.x, a1.y, a1.z, a1.w};
            float bc[8] = {p0.x, p0.y, p0.z, p0.w, p1.x, p1.y, p1.z, p1.w};
#pragma unroll
            for (int r = 0; r < 8; ++r)
#pragma unroll
                for (int c = 0; c < 8; ++c)
                    acc[r][c] += ar[r] * bc[c];
        }
    }
    float4 ba = *(const float4*)(bo + coloff + tx * 4);
    float4 bb = *(const float4*)(bo + coloff + 64 + tx * 4);
#pragma unroll
    for (int r = 0; r < 8; ++r) {
        int grow = row0 + ty * 8 + r;
        if (grow < n) {
            float4 o0, o1;
            o0.x = 1.f / (1.f + __expf(-(acc[r][0] + ba.x)));
            o0.y = 1.f / (1.f + __expf(-(acc[r][1] + ba.y)));
            o0.z = 1.f / (1.f + __expf(-(acc[r][2] + ba.z)));
            o0.w = 1.f / (1.f + __expf(-(acc[r][3] + ba.w)));
            o1.x = 1.f / (1.f + __expf(-(acc[r][4] + bb.x)));
            o1.y = 1.f / (1.f + __expf(-(acc[r][5] + bb.y)));
            o1.z = 1.f / (1.f + __expf(-(acc[r][6] + bb.z)));
            o1.w = 1.f / (1.f + __expf(-(acc[r][7] + bb.w)));
            *(float4*)(out + (size_t)grow * DIN + coloff + tx * 4)      = o0;
            *(float4*)(out + (size_t)grow * DIN + coloff + 64 + tx * 4) = o1;
        }
    }
}

// ---------------- edge aggregation (one wave per node, 8-edge ILP, DPP reduce) --
#define EDGE(ii, xx, vv)                                                  \
    {                                                                      \
        unsigned off = ssb[ii] + lane4;                                    \
        xx = *(const float*)(xlb + off);                                   \
        float s = xx + xrv;                                                \
        vv = attv * (s > 0.f ? s : NEG * s);                               \
    }

__global__ __launch_bounds__(256) void agg_k(const float* __restrict__ xl,
                                             const float* __restrict__ xr,
                                             const float* __restrict__ att,
                                             const float* __restrict__ bias,
                                             const int* __restrict__ offs,
                                             const unsigned* __restrict__ ssb,
                                             float* __restrict__ out, int n) {
    int wave = (blockIdx.x * 256 + threadIdx.x) >> 6;
    int lane = threadIdx.x & 63;
    if (wave >= n) return;
    const char* xlb = (const char*)xl;
    unsigned lane4 = (unsigned)lane * 4u;
    float xrv = xr[(size_t)wave * HC + lane];
    float attv = att[lane];
    float acc = 0.f, den = 0.f;
    int lo = __builtin_amdgcn_readfirstlane(offs[wave]);
    int hi = __builtin_amdgcn_readfirstlane(offs[wave + 1]);
    int i = lo;
    for (; i + 8 <= hi; i += 8) {
        float x0, x1, x2, x3, x4, x5, x6, x7;
        float v0, v1, v2, v3, v4, v5, v6, v7;
        EDGE(i + 0, x0, v0); EDGE(i + 1, x1, v1);
        EDGE(i + 2, x2, v2); EDGE(i + 3, x3, v3);
        EDGE(i + 4, x4, v4); EDGE(i + 5, x5, v5);
        EDGE(i + 6, x6, v6); EDGE(i + 7, x7, v7);
        v0 = reduce16_bcast(v0); v1 = reduce16_bcast(v1);
        v2 = reduce16_bcast(v2); v3 = reduce16_bcast(v3);
        v4 = reduce16_bcast(v4); v5 = reduce16_bcast(v5);
        v6 = reduce16_bcast(v6); v7 = reduce16_bcast(v7);
        float e0 = __expf(v0), e1 = __expf(v1), e2 = __expf(v2), e3 = __expf(v3);
        float e4 = __expf(v4), e5 = __expf(v5), e6 = __expf(v6), e7 = __expf(v7);
        den += ((e0 + e1) + (e2 + e3)) + ((e4 + e5) + (e6 + e7));
        acc += e0 * x0; acc += e1 * x1; acc += e2 * x2; acc += e3 * x3;
        acc += e4 * x4; acc += e5 * x5; acc += e6 * x6; acc += e7 * x7;
    }
    for (; i + 4 <= hi; i += 4) {
        float x0, x1, x2, x3, v0, v1, v2, v3;
        EDGE(i + 0, x0, v0); EDGE(i + 1, x1, v1);
        EDGE(i + 2, x2, v2); EDGE(i + 3, x3, v3);
        v0 = reduce16_bcast(v0); v1 = reduce16_bcast(v1);
        v2 = reduce16_bcast(v2); v3 = reduce16_bcast(v3);
        float e0 = __expf(v0), e1 = __expf(v1), e2 = __expf(v2), e3 = __expf(v3);
        den += (e0 + e1) + (e2 + e3);
        acc += e0 * x0; acc += e1 * x1; acc += e2 * x2; acc += e3 * x3;
    }
    for (; i < hi; ++i) {
        float xv, v;
        EDGE(i, xv, v);
        v = reduce16_bcast(v);
        float ex = __expf(v);
        den += ex;
        acc += ex * xv;
    }
    float o = (den > 0.f) ? acc / den : 0.f;
    o += bias[lane];
    out[(size_t)wave * HC + lane] = fmaxf(o, 0.f);
}

extern "C" void kernel_launch(void* const* d_in, const int* in_sizes, int n_in,
                              void* d_out, int out_size, void* d_ws, size_t ws_size,
                              hipStream_t stream) {
    const float* x    = (const float*)d_in[0];
    const int*   ei   = (const int*)d_in[1];
    const float* Wl1  = (const float*)d_in[2];
    const float* bl1  = (const float*)d_in[3];
    const float* Wr1  = (const float*)d_in[4];
    const float* br1  = (const float*)d_in[5];
    const float* att1 = (const float*)d_in[6];
    const float* bias1= (const float*)d_in[7];
    const float* Wl2  = (const float*)d_in[8];
    const float* bl2  = (const float*)d_in[9];
    const float* Wr2  = (const float*)d_in[10];
    const float* br2  = (const float*)d_in[11];
    const float* att2 = (const float*)d_in[12];
    const float* bias2= (const float*)d_in[13];
    const float* Wo   = (const float*)d_in[14];
    const float* bo   = (const float*)d_in[15];
    float* out = (float*)d_out;

    int E = in_sizes[1] / 2;
    const int* srcv = ei;
    const int* dstv = ei + E;

    size_t NF = (size_t)NN * HC;
    float* xl = (float*)d_ws;
    float* xr = xl + NF;
    float* hb = xr + NF;                  // h1, later h2
    int* offs        = (int*)(hb + NF);   // NN+1
    unsigned* ssrc   = (unsigned*)(offs + NN + 1);  // E (byte offsets)
    int* boffs   = (int*)(ssrc + E);      // NB+1
    int* bcursor = boffs + NB + 1;        // NB
    int* bcnt    = bcursor + NB;          // NB
    // epair scratch lives in d_out (6.4 MB of 51.2 MB), fully consumed
    // before head_gemm_k writes out.
    unsigned* epair = (unsigned*)d_out;

    hipMemsetAsync(bcnt, 0, NB * sizeof(int), stream);
    bhist_k<<<(E + 2047) / 2048, 256, 0, stream>>>(dstv, bcnt, E);
    bscan_k<<<1, 256, 0, stream>>>(bcnt, boffs, bcursor, offs, E);
    bin_k<<<(E + EPB - 1) / EPB, 1024, 0, stream>>>(srcv, dstv, bcursor, epair, E);
    bsort_k<<<NB, 1024, 0, stream>>>(epair, boffs, offs, ssrc, NN);

    int gb = (NN + GM - 1) / GM;
    // layer 1
    gemm_dual_k<<<gb, 256, 0, stream>>>(x, Wl1, bl1, Wr1, br1, xl, xr, NN, DIN);
    agg_k<<<(NN + 3) / 4, 256, 0, stream>>>(xl, xr, att1, bias1, offs, ssrc, hb, NN);
    // layer 2
    gemm_dual_k<<<gb, 256, 0, stream>>>(hb, Wl2, bl2, Wr2, br2, xl, xr, NN, HC);
    agg_k<<<(NN + 3) / 4, 256, 0, stream>>>(xl, xr, att2, bias2, offs, ssrc, hb, NN);
    // head
    head_gemm_k<<<dim3(gb, 2), 256, 0, stream>>>(hb, Wo, bo, out, NN);
}

// Round 6
// 378.319 us; speedup vs baseline: 2.5042x; 1.0152x over previous
//
#include <hip/hip_runtime.h>
#include <math.h>

#define NN 50000
#define DIN 256
#define HC 64
#define NEG 0.2f
#define BK 16
#define TM 64           // gemm rows per block (64 -> grid ~782, 3+ blocks/CU)
#define NB 196          // ceil(NN/256) coarse buckets (dst >> 8)
#define EPB 4096        // edges per bin_k block
#define CAP 36864       // bsort LDS staging capacity (expected bucket ~8192)

// ---- DPP 16-lane reduce+broadcast (quad xor1, xor2, half-mirror, mirror) ----
template <int CTRL>
__device__ __forceinline__ float dpp_mov(float x) {
    int r = __builtin_amdgcn_update_dpp(0, __float_as_int(x), CTRL, 0xF, 0xF, true);
    return __int_as_float(r);
}
__device__ __forceinline__ float reduce16_bcast(float v) {
    v += dpp_mov<0xB1>(v);    // quad_perm [1,0,3,2]  : xor 1
    v += dpp_mov<0x4E>(v);    // quad_perm [2,3,0,1]  : xor 2
    v += dpp_mov<0x141>(v);   // row_half_mirror      : xor 4 on quad sums
    v += dpp_mov<0x140>(v);   // row_mirror           : xor 8
    return v;
}

// ---------------- CSR build: bucketed counting sort ----------------

__global__ __launch_bounds__(256) void bhist_k(const int* __restrict__ dst,
                                               int* __restrict__ bcnt, int E) {
    __shared__ int h[NB];
    int t = threadIdx.x;
    for (int i = t; i < NB; i += 256) h[i] = 0;
    __syncthreads();
    int base = blockIdx.x * 2048 + t;
#pragma unroll
    for (int k = 0; k < 8; ++k) {
        int e = base + k * 256;
        if (e < E) atomicAdd(&h[dst[e] >> 8], 1);
    }
    __syncthreads();
    for (int i = t; i < NB; i += 256)
        if (h[i]) atomicAdd(&bcnt[i], h[i]);
}

__global__ __launch_bounds__(256) void bscan_k(const int* __restrict__ bcnt,
                                               int* __restrict__ boffs,
                                               int* __restrict__ bcursor,
                                               int* __restrict__ offs, int E) {
    __shared__ int s[256];
    int t = threadIdx.x;
    s[t] = (t < NB) ? bcnt[t] : 0;
    __syncthreads();
    for (int off = 1; off < 256; off <<= 1) {
        int v = s[t];
        int u = (t >= off) ? s[t - off] : 0;
        __syncthreads();
        s[t] = v + u;
        __syncthreads();
    }
    if (t < NB) {
        int ex = (t == 0) ? 0 : s[t - 1];
        boffs[t] = ex;
        bcursor[t] = ex;
    }
    if (t == NB) boffs[NB] = s[NB - 1];
    if (t == 0) offs[NN] = E;
}

__global__ __launch_bounds__(1024) void bin_k(const int* __restrict__ src,
                                              const int* __restrict__ dst,
                                              int* __restrict__ bcursor,
                                              unsigned* __restrict__ epair, int E) {
    __shared__ int hist[NB];
    __shared__ int lofs[NB];
    __shared__ int gshift[NB];
    __shared__ int scanb[256];
    __shared__ unsigned pbuf[EPB];
    __shared__ unsigned char abkt[EPB];
    int t = threadIdx.x;
    for (int i = t; i < NB; i += 1024) hist[i] = 0;
    __syncthreads();
    int e0 = blockIdx.x * EPB;
    unsigned p[4]; int bk[4], rk[4]; bool val[4];
#pragma unroll
    for (int k = 0; k < 4; ++k) {
        int e = e0 + k * 1024 + t;
        val[k] = e < E;
        if (val[k]) {
            int s = src[e], d = dst[e];
            p[k] = ((unsigned)s << 8) | (unsigned)(d & 255);
            bk[k] = d >> 8;
            rk[k] = atomicAdd(&hist[bk[k]], 1);
        }
    }
    __syncthreads();
    if (t < 256) scanb[t] = (t < NB) ? hist[t] : 0;
    __syncthreads();
    for (int off = 1; off < 256; off <<= 1) {
        int v = 0, u = 0;
        if (t < 256) { v = scanb[t]; if (t >= off) u = scanb[t - off]; }
        __syncthreads();
        if (t < 256) scanb[t] = v + u;
        __syncthreads();
    }
    if (t < NB) {
        int ex = (t == 0) ? 0 : scanb[t - 1];
        lofs[t] = ex;
        int gb = atomicAdd(&bcursor[t], hist[t]);
        gshift[t] = gb - ex;
    }
    __syncthreads();
    int total = scanb[NB - 1];
#pragma unroll
    for (int k = 0; k < 4; ++k) {
        if (val[k]) {
            int pos = lofs[bk[k]] + rk[k];
            pbuf[pos] = p[k];
            abkt[pos] = (unsigned char)bk[k];
        }
    }
    __syncthreads();
    for (int i = t; i < total; i += 1024) {
        int b = abkt[i];
        epair[gshift[b] + i] = pbuf[i];
    }
}

// per-bucket counting sort; ssrc holds BYTE offsets (src*HC*4 == src<<8)
__global__ __launch_bounds__(1024) void bsort_k(const unsigned* __restrict__ epair,
                                                const int* __restrict__ boffs,
                                                int* __restrict__ offs,
                                                unsigned* __restrict__ ssrc, int n) {
    __shared__ int lhist[256];
    __shared__ int lcur[256];
    __shared__ int scanb[256];
    __shared__ unsigned sbuf[CAP];
    int b = blockIdx.x, t = threadIdx.x;
    int start = boffs[b], end = boffs[b + 1];
    int cnt = end - start;
    if (t < 256) lhist[t] = 0;
    __syncthreads();
    for (int i = t; i < cnt; i += 1024) {
        unsigned p = epair[start + i];
        atomicAdd(&lhist[p & 255], 1);
    }
    __syncthreads();
    if (t < 256) scanb[t] = lhist[t];
    __syncthreads();
    for (int off = 1; off < 256; off <<= 1) {
        int v = 0, u = 0;
        if (t < 256) { v = scanb[t]; if (t >= off) u = scanb[t - off]; }
        __syncthreads();
        if (t < 256) scanb[t] = v + u;
        __syncthreads();
    }
    if (t < 256) {
        int ex = (t == 0) ? 0 : scanb[t - 1];
        lcur[t] = ex;
        int node = b * 256 + t;
        if (node < n) offs[node] = start + ex;
    }
    __syncthreads();
    if (cnt <= CAP) {
        for (int i = t; i < cnt; i += 1024) {
            unsigned p = epair[start + i];
            int r = atomicAdd(&lcur[p & 255], 1);
            sbuf[r] = p & ~255u;           // src<<8 = byte offset into xl
        }
        __syncthreads();
        for (int i = t; i < cnt; i += 1024) ssrc[start + i] = sbuf[i];
    } else {
        for (int i = t; i < cnt; i += 1024) {
            unsigned p = epair[start + i];
            int r = atomicAdd(&lcur[p & 255], 1);
            ssrc[start + r] = p & ~255u;
        }
    }
}

// ---------------- tiled dual GEMM: [xl|xr] = A @ [Wl|Wr] + [bl|br] ----------------
// tile 64 rows x 128 cols, BK=16; each thread 4 rows x (4+4) cols.
// All LDS strides are 4 dwords -> <=2-way aliasing (free).
__global__ __launch_bounds__(256) void gemm_dual_k(const float* __restrict__ A,
                                                   const float* __restrict__ Wl,
                                                   const float* __restrict__ bl,
                                                   const float* __restrict__ Wr,
                                                   const float* __restrict__ br,
                                                   float* __restrict__ xl,
                                                   float* __restrict__ xr,
                                                   int n, int K) {
    __shared__ float As[BK][TM + 4];
    __shared__ float Bs[BK][128];
    int t = threadIdx.x;
    int tx = t & 15, ty = t >> 4;
    int row0 = blockIdx.x * TM;
    float acc[4][8] = {};
    int arow = t >> 2;             // 0..63
    int akb  = (t & 3) * 4;        // 0,4,8,12
    int bk   = t >> 4;             // 0..15
    int bcol = (t & 15) * 4;       // 0..60
    bool arow_ok = (row0 + arow) < n;
    const float* Aptr = A + (size_t)(row0 + arow) * K + akb;

    for (int kc = 0; kc < K; kc += BK) {
        float4 av = make_float4(0.f, 0.f, 0.f, 0.f);
        if (arow_ok) av = *(const float4*)(Aptr + kc);
        float4 b0 = *(const float4*)(Wl + (size_t)(kc + bk) * HC + bcol);
        float4 b1 = *(const float4*)(Wr + (size_t)(kc + bk) * HC + bcol);
        __syncthreads();
        As[akb + 0][arow] = av.x;
        As[akb + 1][arow] = av.y;
        As[akb + 2][arow] = av.z;
        As[akb + 3][arow] = av.w;
        *(float4*)&Bs[bk][bcol]      = b0;
        *(float4*)&Bs[bk][64 + bcol] = b1;
        __syncthreads();
#pragma unroll
        for (int k = 0; k < BK; ++k) {
            float4 a  = *(const float4*)&As[k][ty * 4];
            float4 p0 = *(const float4*)&Bs[k][tx * 4];
            float4 p1 = *(const float4*)&Bs[k][64 + tx * 4];
            float ar[4] = {a.x, a.y, a.z, a.w};
            float bc[8] = {p0.x, p0.y, p0.z, p0.w, p1.x, p1.y, p1.z, p1.w};
#pragma unroll
            for (int r = 0; r < 4; ++r)
#pragma unroll
                for (int c = 0; c < 8; ++c)
                    acc[r][c] += ar[r] * bc[c];
        }
    }
    float4 bl4 = *(const float4*)(bl + tx * 4);
    float4 br4 = *(const float4*)(br + tx * 4);
#pragma unroll
    for (int r = 0; r < 4; ++r) {
        int grow = row0 + ty * 4 + r;
        if (grow < n) {
            float4 ol, orr;
            ol.x = acc[r][0] + bl4.x; ol.y = acc[r][1] + bl4.y;
            ol.z = acc[r][2] + bl4.z; ol.w = acc[r][3] + bl4.w;
            orr.x = acc[r][4] + br4.x; orr.y = acc[r][5] + br4.y;
            orr.z = acc[r][6] + br4.z; orr.w = acc[r][7] + br4.w;
            *(float4*)(xl + (size_t)grow * HC + tx * 4) = ol;
            *(float4*)(xr + (size_t)grow * HC + tx * 4) = orr;
        }
    }
}

// ---------------- head GEMM: out = sigmoid(h @ Wo + bo) ----------------
// tile 64 rows x 128 cols (gridDim.y = 2 for the 256 out cols)
__global__ __launch_bounds__(256) void head_gemm_k(const float* __restrict__ h,
                                                   const float* __restrict__ Wo,
                                                   const float* __restrict__ bo,
                                                   float* __restrict__ out, int n) {
    __shared__ float As[BK][TM + 4];
    __shared__ float Bs[BK][128];
    int t = threadIdx.x;
    int tx = t & 15, ty = t >> 4;
    int row0 = blockIdx.x * TM;
    int coloff = blockIdx.y * 128;
    float acc[4][8] = {};
    int arow = t >> 2;
    int akb  = (t & 3) * 4;
    int bk   = t >> 4;
    int bcol = (t & 15) * 4;
    bool arow_ok = (row0 + arow) < n;
    const float* Aptr = h + (size_t)(row0 + arow) * HC + akb;

    for (int kc = 0; kc < HC; kc += BK) {
        float4 av = make_float4(0.f, 0.f, 0.f, 0.f);
        if (arow_ok) av = *(const float4*)(Aptr + kc);
        float4 b0 = *(const float4*)(Wo + (size_t)(kc + bk) * DIN + coloff + bcol);
        float4 b1 = *(const float4*)(Wo + (size_t)(kc + bk) * DIN + coloff + 64 + bcol);
        __syncthreads();
        As[akb + 0][arow] = av.x;
        As[akb + 1][arow] = av.y;
        As[akb + 2][arow] = av.z;
        As[akb + 3][arow] = av.w;
        *(float4*)&Bs[bk][bcol]      = b0;
        *(float4*)&Bs[bk][64 + bcol] = b1;
        __syncthreads();
#pragma unroll
        for (int k = 0; k < BK; ++k) {
            float4 a  = *(const float4*)&As[k][ty * 4];
            float4 p0 = *(const float4*)&Bs[k][tx * 4];
            float4 p1 = *(const float4*)&Bs[k][64 + tx * 4];
            float ar[4] = {a.x, a.y, a.z, a.w};
            float bc[8] = {p0.x, p0.y, p0.z, p0.w, p1.x, p1.y, p1.z, p1.w};
#pragma unroll
            for (int r = 0; r < 4; ++r)
#pragma unroll
                for (int c = 0; c < 8; ++c)
                    acc[r][c] += ar[r] * bc[c];
        }
    }
    float4 ba = *(const float4*)(bo + coloff + tx * 4);
    float4 bb = *(const float4*)(bo + coloff + 64 + tx * 4);
#pragma unroll
    for (int r = 0; r < 4; ++r) {
        int grow = row0 + ty * 4 + r;
        if (grow < n) {
            float4 o0, o1;
            o0.x = 1.f / (1.f + __expf(-(acc[r][0] + ba.x)));
            o0.y = 1.f / (1.f + __expf(-(acc[r][1] + ba.y)));
            o0.z = 1.f / (1.f + __expf(-(acc[r][2] + ba.z)));
            o0.w = 1.f / (1.f + __expf(-(acc[r][3] + ba.w)));
            o1.x = 1.f / (1.f + __expf(-(acc[r][4] + bb.x)));
            o1.y = 1.f / (1.f + __expf(-(acc[r][5] + bb.y)));
            o1.z = 1.f / (1.f + __expf(-(acc[r][6] + bb.z)));
            o1.w = 1.f / (1.f + __expf(-(acc[r][7] + bb.w)));
            *(float4*)(out + (size_t)grow * DIN + coloff + tx * 4)      = o0;
            *(float4*)(out + (size_t)grow * DIN + coloff + 64 + tx * 4) = o1;
        }
    }
}

// ---------------- edge aggregation (one wave per node, 8-edge ILP, DPP reduce) --
#define EDGE(ii, xx, vv)                                                  \
    {                                                                      \
        unsigned off = ssb[ii] + lane4;                                    \
        xx = *(const float*)(xlb + off);                                   \
        float s = xx + xrv;                                                \
        vv = attv * (s > 0.f ? s : NEG * s);                               \
    }

__global__ __launch_bounds__(256) void agg_k(const float* __restrict__ xl,
                                             const float* __restrict__ xr,
                                             const float* __restrict__ att,
                                             const float* __restrict__ bias,
                                             const int* __restrict__ offs,
                                             const unsigned* __restrict__ ssb,
                                             float* __restrict__ out, int n) {
    int wave = (blockIdx.x * 256 + threadIdx.x) >> 6;
    int lane = threadIdx.x & 63;
    if (wave >= n) return;
    const char* xlb = (const char*)xl;
    unsigned lane4 = (unsigned)lane * 4u;
    float xrv = xr[(size_t)wave * HC + lane];
    float attv = att[lane];
    float acc = 0.f, den = 0.f;
    int lo = __builtin_amdgcn_readfirstlane(offs[wave]);
    int hi = __builtin_amdgcn_readfirstlane(offs[wave + 1]);
    int i = lo;
    for (; i + 8 <= hi; i += 8) {
        float x0, x1, x2, x3, x4, x5, x6, x7;
        float v0, v1, v2, v3, v4, v5, v6, v7;
        EDGE(i + 0, x0, v0); EDGE(i + 1, x1, v1);
        EDGE(i + 2, x2, v2); EDGE(i + 3, x3, v3);
        EDGE(i + 4, x4, v4); EDGE(i + 5, x5, v5);
        EDGE(i + 6, x6, v6); EDGE(i + 7, x7, v7);
        v0 = reduce16_bcast(v0); v1 = reduce16_bcast(v1);
        v2 = reduce16_bcast(v2); v3 = reduce16_bcast(v3);
        v4 = reduce16_bcast(v4); v5 = reduce16_bcast(v5);
        v6 = reduce16_bcast(v6); v7 = reduce16_bcast(v7);
        float e0 = __expf(v0), e1 = __expf(v1), e2 = __expf(v2), e3 = __expf(v3);
        float e4 = __expf(v4), e5 = __expf(v5), e6 = __expf(v6), e7 = __expf(v7);
        den += ((e0 + e1) + (e2 + e3)) + ((e4 + e5) + (e6 + e7));
        acc += e0 * x0; acc += e1 * x1; acc += e2 * x2; acc += e3 * x3;
        acc += e4 * x4; acc += e5 * x5; acc += e6 * x6; acc += e7 * x7;
    }
    for (; i + 4 <= hi; i += 4) {
        float x0, x1, x2, x3, v0, v1, v2, v3;
        EDGE(i + 0, x0, v0); EDGE(i + 1, x1, v1);
        EDGE(i + 2, x2, v2); EDGE(i + 3, x3, v3);
        v0 = reduce16_bcast(v0); v1 = reduce16_bcast(v1);
        v2 = reduce16_bcast(v2); v3 = reduce16_bcast(v3);
        float e0 = __expf(v0), e1 = __expf(v1), e2 = __expf(v2), e3 = __expf(v3);
        den += (e0 + e1) + (e2 + e3);
        acc += e0 * x0; acc += e1 * x1; acc += e2 * x2; acc += e3 * x3;
    }
    for (; i < hi; ++i) {
        float xv, v;
        EDGE(i, xv, v);
        v = reduce16_bcast(v);
        float ex = __expf(v);
        den += ex;
        acc += ex * xv;
    }
    float o = (den > 0.f) ? acc / den : 0.f;
    o += bias[lane];
    out[(size_t)wave * HC + lane] = fmaxf(o, 0.f);
}

extern "C" void kernel_launch(void* const* d_in, const int* in_sizes, int n_in,
                              void* d_out, int out_size, void* d_ws, size_t ws_size,
                              hipStream_t stream) {
    const float* x    = (const float*)d_in[0];
    const int*   ei   = (const int*)d_in[1];
    const float* Wl1  = (const float*)d_in[2];
    const float* bl1  = (const float*)d_in[3];
    const float* Wr1  = (const float*)d_in[4];
    const float* br1  = (const float*)d_in[5];
    const float* att1 = (const float*)d_in[6];
    const float* bias1= (const float*)d_in[7];
    const float* Wl2  = (const float*)d_in[8];
    const float* bl2  = (const float*)d_in[9];
    const float* Wr2  = (const float*)d_in[10];
    const float* br2  = (const float*)d_in[11];
    const float* att2 = (const float*)d_in[12];
    const float* bias2= (const float*)d_in[13];
    const float* Wo   = (const float*)d_in[14];
    const float* bo   = (const float*)d_in[15];
    float* out = (float*)d_out;

    int E = in_sizes[1] / 2;
    const int* srcv = ei;
    const int* dstv = ei + E;

    size_t NF = (size_t)NN * HC;
    float* xl = (float*)d_ws;
    float* xr = xl + NF;
    float* hb = xr + NF;                  // h1, later h2
    int* offs        = (int*)(hb + NF);   // NN+1
    unsigned* ssrc   = (unsigned*)(offs + NN + 1);  // E (byte offsets)
    int* boffs   = (int*)(ssrc + E);      // NB+1
    int* bcursor = boffs + NB + 1;        // NB
    int* bcnt    = bcursor + NB;          // NB
    // epair scratch lives in d_out (6.4 MB of 51.2 MB), fully consumed
    // before head_gemm_k writes out.
    unsigned* epair = (unsigned*)d_out;

    hipMemsetAsync(bcnt, 0, NB * sizeof(int), stream);
    bhist_k<<<(E + 2047) / 2048, 256, 0, stream>>>(dstv, bcnt, E);
    bscan_k<<<1, 256, 0, stream>>>(bcnt, boffs, bcursor, offs, E);
    bin_k<<<(E + EPB - 1) / EPB, 1024, 0, stream>>>(srcv, dstv, bcursor, epair, E);
    bsort_k<<<NB, 1024, 0, stream>>>(epair, boffs, offs, ssrc, NN);

    int gb = (NN + TM - 1) / TM;
    // layer 1
    gemm_dual_k<<<gb, 256, 0, stream>>>(x, Wl1, bl1, Wr1, br1, xl, xr, NN, DIN);
    agg_k<<<(NN + 3) / 4, 256, 0, stream>>>(xl, xr, att1, bias1, offs, ssrc, hb, NN);
    // layer 2
    gemm_dual_k<<<gb, 256, 0, stream>>>(hb, Wl2, bl2, Wr2, br2, xl, xr, NN, HC);
    agg_k<<<(NN + 3) / 4, 256, 0, stream>>>(xl, xr, att2, bias2, offs, ssrc, hb, NN);
    // head
    head_gemm_k<<<dim3(gb, 2), 256, 0, stream>>>(hb, Wo, bo, out, NN);
}